// Round 9
// baseline (450.004 us; speedup 1.0000x reference)
//
#include <hip/hip_runtime.h>
#include <hip/hip_fp16.h>

#define N_NODES   50000
#define N_EDGES   1600000
#define CH        128
#define OUTC      2
#define NGRAPHS   64

#define NBUCK     391          // ceil(N_NODES / 128)
#define EPB       4096         // edges per block in edge-parallel kernels
#define F1BLOCKS  391          // ceil(N_EDGES / EPB)
#define BCAP      5120         // max bucket size handled in LDS

#define GR        64           // gemm rows per block
#define NSLAB     4            // channel slabs (32 ch each)
#define SLABH2    ((size_t)N_NODES * 16)   // half2 elements per slab

using f16x8 = __attribute__((ext_vector_type(8))) _Float16;
using f32x4 = __attribute__((ext_vector_type(4))) float;

// ---------------- CSR build (bucket-level, no per-node atomics) ----------------

__global__ __launch_bounds__(256) void bhist_k(const int* __restrict__ dst,
                                               int* __restrict__ bhist) {
    __shared__ int hist[NBUCK];
    const int tid = threadIdx.x;
    const int e0  = blockIdx.x * EPB;
    const int nE  = min(EPB, N_EDGES - e0);
    for (int i = tid; i < NBUCK; i += 256) hist[i] = 0;
    __syncthreads();
    for (int i = tid; i < nE; i += 256) atomicAdd(&hist[dst[e0 + i] >> 7], 1);
    __syncthreads();
    for (int i = tid; i < NBUCK; i += 256) if (hist[i]) atomicAdd(&bhist[i], hist[i]);
}

__global__ __launch_bounds__(512) void bscan_k(const int* __restrict__ bhist,
                                               int* __restrict__ bbase,
                                               int* __restrict__ bcur) {
    const int t = threadIdx.x, lane = t & 63, w = t >> 6;
    int v = (t < NBUCK) ? bhist[t] : 0;
    int iv = v;
    #pragma unroll
    for (int d = 1; d < 64; d <<= 1) {
        int o = __shfl_up(iv, d, 64);
        if (lane >= d) iv += o;
    }
    __shared__ int ws[8];
    if (lane == 63) ws[w] = iv;
    __syncthreads();
    int add = 0;
    #pragma unroll
    for (int k = 0; k < 8; k++) if (k < w) add += ws[k];
    int excl = add + iv - v;
    if (t < NBUCK) { bbase[t] = excl; bcur[t] = excl; }
    if (t == NBUCK - 1) bbase[NBUCK] = excl + v;
}

// scatter packed (src | ldst<<16) into bucket-contiguous staging
__global__ __launch_bounds__(256) void bucket_scatter_k(const int* __restrict__ src,
                                                        const int* __restrict__ dst,
                                                        int* __restrict__ bucketCursor,
                                                        int* __restrict__ stage) {
    __shared__ int hist[NBUCK];
    __shared__ int cur[NBUCK];
    __shared__ int gbase[NBUCK];
    const int tid = threadIdx.x;
    const int e0  = blockIdx.x * EPB;
    const int nE  = min(EPB, N_EDGES - e0);

    for (int i = tid; i < NBUCK; i += 256) hist[i] = 0;
    __syncthreads();
    for (int i = tid; i < nE; i += 256) {
        int d = dst[e0 + i];
        atomicAdd(&hist[d >> 7], 1);
    }
    __syncthreads();
    for (int i = tid; i < NBUCK; i += 256) {
        int h = hist[i];
        gbase[i] = h ? atomicAdd(&bucketCursor[i], h) : 0;
        cur[i] = 0;
    }
    __syncthreads();
    for (int i = tid; i < nE; i += 256) {
        int d = dst[e0 + i];
        int s = src[e0 + i];
        int b = d >> 7;
        int pos = gbase[b] + atomicAdd(&cur[b], 1);
        stage[pos] = s | ((d & 127) << 16);
    }
}

__global__ __launch_bounds__(256) void bucket_build_k(const int* __restrict__ stage,
                                                      const int* __restrict__ bbase,
                                                      int* __restrict__ offsets,
                                                      float* __restrict__ dis,
                                                      int* __restrict__ csr) {
    __shared__ int lcnt[128];
    __shared__ int lcur[128];
    __shared__ int wtot[2];
    __shared__ int loc[BCAP];
    const int tid    = threadIdx.x;
    const int b      = blockIdx.x;
    const int first  = b << 7;
    const int nNodes = min(128, N_NODES - first);
    const int base   = bbase[b];
    const int bsize  = bbase[b + 1] - base;

    if (tid < 128) lcnt[tid] = 0;
    __syncthreads();
    for (int i = tid; i < bsize; i += 256)
        atomicAdd(&lcnt[((unsigned)stage[base + i]) >> 16], 1);
    __syncthreads();

    int iv = 0, c = 0;
    if (tid < 128) {
        c = lcnt[tid];
        iv = c;
        #pragma unroll
        for (int d = 1; d < 64; d <<= 1) {
            int o = __shfl_up(iv, d, 64);
            if ((tid & 63) >= d) iv += o;
        }
        if ((tid & 63) == 63) wtot[tid >> 6] = iv;
    }
    __syncthreads();
    if (tid < 128) {
        int add  = (tid >= 64) ? wtot[0] : 0;
        int excl = add + iv - c;
        lcur[tid] = excl;
        if (tid < nNodes) {
            offsets[first + tid] = base + excl;
            dis[first + tid]     = rsqrtf((float)(c + 1));
        }
    }
    if (b == NBUCK - 1 && tid == 0) offsets[N_NODES] = base + bsize;
    __syncthreads();

    if (bsize <= BCAP) {
        for (int i = tid; i < bsize; i += 256) {
            int sd = stage[base + i];
            int pos = atomicAdd(&lcur[((unsigned)sd) >> 16], 1);
            loc[pos] = sd & 0xFFFF;
        }
        __syncthreads();
        for (int i = tid; i < bsize; i += 256) csr[base + i] = loc[i];
    } else {
        for (int i = tid; i < bsize; i += 256) {
            int sd = stage[base + i];
            int pos = atomicAdd(&lcur[((unsigned)sd) >> 16], 1);
            csr[base + pos] = sd & 0xFFFF;
        }
    }
}

// ---------------- graph ranges from sorted batch ----------------
__global__ __launch_bounds__(256) void boundary_k(const int* __restrict__ batch,
                                                  int* __restrict__ gstart) {
    int i = blockIdx.x * 256 + threadIdx.x;
    if (i >= N_NODES) return;
    int bc = batch[i];
    if (i == 0) {
        for (int g = 0; g <= bc; g++) gstart[g] = 0;
    } else {
        int bp = batch[i - 1];
        for (int g = bp + 1; g <= bc; g++) gstart[g] = i;
    }
    if (i == N_NODES - 1) {
        for (int g = bc + 1; g <= NGRAPHS; g++) gstart[g] = N_NODES;
    }
}

// ---------------- W -> fp16 transpose: Wt[c][k] = W[k][c] ----------------
__global__ __launch_bounds__(256) void prep_w_k(const float* __restrict__ W0,
                                                const float* __restrict__ W1,
                                                const float* __restrict__ W2,
                                                __half* __restrict__ T0,
                                                __half* __restrict__ T1,
                                                __half* __restrict__ T2) {
    const float* W = (blockIdx.x == 0) ? W0 : (blockIdx.x == 1) ? W1 : W2;
    __half* Wt     = (blockIdx.x == 0) ? T0 : (blockIdx.x == 1) ? T1 : T2;
    for (int i = threadIdx.x; i < CH * CH; i += 256) {
        int k = i >> 7, c = i & 127;
        Wt[c * CH + k] = __float2half(W[i]);
    }
}

// ---------------- MFMA GEMM: hs = (h @ W) * dis[row], fp16 slab-layout out ----------------
// slab layout: slab q (channels q*32..q*32+31) at base q*N_NODES*32 halfs, row n at n*32.
template <bool F32IN>
__global__ __launch_bounds__(256) void gemm_mfma_k(const void* __restrict__ hin,
                                                   const __half* __restrict__ Wt,
                                                   const float* __restrict__ dis,
                                                   __half* __restrict__ out) {
    __shared__ _Float16 Hl[GR][136];    // 17.4 KB
    __shared__ _Float16 Wl[CH][136];    // 34.8 KB
    const int tid = threadIdx.x;
    const int rowBase = blockIdx.x * GR;

    // stage Wt: thread -> col c = tid>>1, half q = tid&1 (8 x 16B)
    {
        const int c = tid >> 1, q = tid & 1;
        #pragma unroll
        for (int i = 0; i < 8; i++)
            *(f16x8*)&Wl[c][q * 64 + i * 8] =
                *(const f16x8*)&Wt[c * CH + q * 64 + i * 8];
    }
    // stage H: thread -> row r = tid>>2, quarter/slab q = tid&3 (32 halfs)
    {
        const int r = tid >> 2, q = tid & 3;
        const int n = rowBase + r;
        if constexpr (F32IN) {
            const float* h = (const float*)hin;
            #pragma unroll
            for (int i = 0; i < 8; i++) {
                float4 v = make_float4(0.f, 0.f, 0.f, 0.f);
                if (n < N_NODES) v = *(const float4*)&h[(size_t)n * CH + q * 32 + i * 4];
                *(__half2*)&Hl[r][q * 32 + i * 4]     = __floats2half2_rn(v.x, v.y);
                *(__half2*)&Hl[r][q * 32 + i * 4 + 2] = __floats2half2_rn(v.z, v.w);
            }
        } else {
            const _Float16* h = (const _Float16*)hin + (size_t)q * N_NODES * 32;
            #pragma unroll
            for (int i = 0; i < 4; i++) {
                f16x8 v = {};
                if (n < N_NODES) v = *(const f16x8*)&h[(size_t)n * 32 + i * 8];
                *(f16x8*)&Hl[r][q * 32 + i * 8] = v;
            }
        }
    }
    __syncthreads();

    const int w = tid >> 6, lane = tid & 63;
    const int l15 = lane & 15, kg = lane >> 4;

    f32x4 acc[8];
    #pragma unroll
    for (int t = 0; t < 8; t++) acc[t] = (f32x4){0.f, 0.f, 0.f, 0.f};

    #pragma unroll
    for (int kt = 0; kt < 4; kt++) {
        f16x8 a = *(f16x8*)&Hl[w * 16 + l15][kt * 32 + kg * 8];
        #pragma unroll
        for (int t = 0; t < 8; t++) {
            f16x8 b = *(f16x8*)&Wl[t * 16 + l15][kt * 32 + kg * 8];
            acc[t] = __builtin_amdgcn_mfma_f32_16x16x32_f16(a, b, acc[t], 0, 0, 0);
        }
    }
    __syncthreads();   // all waves done reading Hl

    // write scaled C into Hl (fp16), rows are wave-private
    #pragma unroll
    for (int r = 0; r < 4; r++) {
        const int lrow = w * 16 + kg * 4 + r;
        const int n = rowBase + lrow;
        const float s = (n < N_NODES) ? dis[n] : 0.f;
        #pragma unroll
        for (int t = 0; t < 8; t++)
            Hl[lrow][t * 16 + l15] = (_Float16)(acc[t][r] * s);
    }
    __syncthreads();

    // coalesced stream-out to slab layout
    {
        const int r = tid >> 2, q = tid & 3;
        const int n = rowBase + r;
        if (n < N_NODES) {
            _Float16* o = (_Float16*)out + (size_t)q * N_NODES * 32;
            #pragma unroll
            for (int i = 0; i < 4; i++)
                *(f16x8*)&o[(size_t)n * 32 + i * 8] = *(f16x8*)&Hl[r][q * 32 + i * 8];
        }
    }
}

// ---------------- Aggregate (channel-split): per pass p, slab-resident gather ----------------
// h[n, p*32..] = relu(dis[n]*(sum_e hs[src_e] + hs[n]) + b); 16 lanes/edge, 4 edges/instr.
__global__ __launch_bounds__(256) void agg_k(const __half* __restrict__ hs,
                                             const int* __restrict__ offsets,
                                             const int* __restrict__ csr,
                                             const float* __restrict__ dis,
                                             const float* __restrict__ bias,
                                             __half* __restrict__ out) {
    const int p    = blockIdx.y;               // slab 0..3
    const int wid  = threadIdx.x >> 6;
    const int lane = threadIdx.x & 63;
    const int n = blockIdx.x * 4 + wid;
    if (n >= N_NODES) return;
    const int eg = lane >> 4;                  // edge group 0..3
    const int d  = lane & 15;                  // dword within row (2 ch)
    const __half2* slab = (const __half2*)hs + (size_t)p * SLABH2;

    float2 acc = make_float2(0.f, 0.f);
    if (eg == 0) {
        float2 v = __half22float2(slab[(size_t)n * 16 + d]);
        acc.x = v.x; acc.y = v.y;              // self-loop once
    }

    const int beg = offsets[n];
    const int end = offsets[n + 1];
    const int last = end - 1;
    for (int e = beg; e < end; e += 16) {
        int t0 = e + eg, t1 = e + 4 + eg, t2 = e + 8 + eg, t3 = e + 12 + eg;
        int i0 = csr[min(t0, last)];
        int i1 = csr[min(t1, last)];
        int i2 = csr[min(t2, last)];
        int i3 = csr[min(t3, last)];
        __half2 v0 = slab[(size_t)i0 * 16 + d];
        __half2 v1 = slab[(size_t)i1 * 16 + d];
        __half2 v2 = slab[(size_t)i2 * 16 + d];
        __half2 v3 = slab[(size_t)i3 * 16 + d];
        if (t0 < end) { float2 f = __half22float2(v0); acc.x += f.x; acc.y += f.y; }
        if (t1 < end) { float2 f = __half22float2(v1); acc.x += f.x; acc.y += f.y; }
        if (t2 < end) { float2 f = __half22float2(v2); acc.x += f.x; acc.y += f.y; }
        if (t3 < end) { float2 f = __half22float2(v3); acc.x += f.x; acc.y += f.y; }
    }

    // combine the 4 edge-groups (channels match across groups)
    acc.x += __shfl_xor(acc.x, 16); acc.y += __shfl_xor(acc.y, 16);
    acc.x += __shfl_xor(acc.x, 32); acc.y += __shfl_xor(acc.y, 32);

    if (eg == 0) {
        const float dn = dis[n];
        float2 b = *(const float2*)&bias[p * 32 + d * 2];
        float rx = fmaxf(dn * acc.x + b.x, 0.f);
        float ry = fmaxf(dn * acc.y + b.y, 0.f);
        ((__half2*)out)[(size_t)p * SLABH2 + (size_t)n * 16 + d] = __floats2half2_rn(rx, ry);
    }
}

// ---------------- Global mean pool over fp16 slab h: grid (8 chunks, 64 graphs) ----------------
__global__ __launch_bounds__(256) void pool_k(const __half* __restrict__ h,
                                              const int* __restrict__ gstart,
                                              float* __restrict__ gsum) {
    const int g   = blockIdx.y;
    const int s   = blockIdx.x;        // chunk 0..7
    const int tid = threadIdx.x;
    const int r   = tid >> 5;          // 0..7 row slot
    const int cq  = tid & 31;          // channel quad: channels cq*4..+3
    const __half2* slab = (const __half2*)h + (size_t)(cq >> 3) * SLABH2;
    const int dw = (cq & 7) * 2;
    const int start = gstart[g], end = gstart[g + 1];
    const int len   = end - start;
    const int chunk = (len + 7) >> 3;
    const int lo = start + s * chunk;
    const int hi = min(lo + chunk, end);

    float4 acc = make_float4(0.f, 0.f, 0.f, 0.f);
    for (int row = lo + r; row < hi; row += 8) {
        float2 a = __half22float2(slab[(size_t)row * 16 + dw]);
        float2 b = __half22float2(slab[(size_t)row * 16 + dw + 1]);
        acc.x += a.x; acc.y += a.y; acc.z += b.x; acc.w += b.y;
    }

    __shared__ float4 red[256];
    red[tid] = acc;
    __syncthreads();
    #pragma unroll
    for (int off = 4; off >= 1; off >>= 1) {
        if (r < off) {
            float4 o = red[tid + off * 32];
            red[tid].x += o.x; red[tid].y += o.y;
            red[tid].z += o.z; red[tid].w += o.w;
        }
        __syncthreads();
    }
    if (r == 0) {
        float4 v = red[tid];
        atomicAdd(&gsum[g * CH + cq * 4 + 0], v.x);
        atomicAdd(&gsum[g * CH + cq * 4 + 1], v.y);
        atomicAdd(&gsum[g * CH + cq * 4 + 2], v.z);
        atomicAdd(&gsum[g * CH + cq * 4 + 3], v.w);
    }
}

// ---------------- Head ----------------
__global__ __launch_bounds__(128) void head_k(const float* __restrict__ gsum,
                                              const int* __restrict__ gstart,
                                              const float* __restrict__ Wlin,
                                              const float* __restrict__ blin,
                                              float* __restrict__ out) {
    const int t = threadIdx.x;      // 0..127
    const int g = t >> 1;
    const int o = t & 1;
    float cnt = (float)max(gstart[g + 1] - gstart[g], 1);
    float s = 0.f;
    for (int ci = 0; ci < CH; ci++) s += gsum[g * CH + ci] * Wlin[ci * OUTC + o];
    out[g * OUTC + o] = s / cnt + blin[o];
}

// ---------------- launch ----------------

static inline size_t alignup(size_t x) { return (x + 255) & ~(size_t)255; }

extern "C" void kernel_launch(void* const* d_in, const int* in_sizes, int n_in,
                              void* d_out, int out_size, void* d_ws, size_t ws_size,
                              hipStream_t stream) {
    const float* x     = (const float*)d_in[0];
    const int*   eidx  = (const int*)d_in[1];
    const int*   batch = (const int*)d_in[2];
    const float* W0    = (const float*)d_in[3];
    const float* b0    = (const float*)d_in[4];
    const float* W1    = (const float*)d_in[5];
    const float* b1    = (const float*)d_in[6];
    const float* W2    = (const float*)d_in[7];
    const float* b2    = (const float*)d_in[8];
    const float* Wlin  = (const float*)d_in[9];
    const float* blin  = (const float*)d_in[10];
    float* out = (float*)d_out;

    const int* src = eidx;
    const int* dst = eidx + N_EDGES;

    char* p = (char*)d_ws;
    int*    offsets = (int*)p;     p += alignup((N_NODES + 1) * 4);
    float*  dis     = (float*)p;   p += alignup(N_NODES * 4);
    int*    bhist   = (int*)p;     p += alignup(NBUCK * 4);
    int*    bbase   = (int*)p;     p += alignup((NBUCK + 1) * 4);
    int*    bcur    = (int*)p;     p += alignup(NBUCK * 4);
    int*    gstart  = (int*)p;     p += alignup((NGRAPHS + 1) * 4);
    int*    csr     = (int*)p;     p += alignup((size_t)N_EDGES * 4);
    __half* Wt0     = (__half*)p;  p += alignup(CH * CH * 2);
    __half* Wt1     = (__half*)p;  p += alignup(CH * CH * 2);
    __half* Wt2     = (__half*)p;  p += alignup(CH * CH * 2);
    __half* bufA    = (__half*)p;  p += alignup((size_t)N_NODES * CH * 2);
    __half* hsbuf   = (__half*)p;  p += alignup((size_t)N_NODES * CH * 2);
    int*    stage   = (int*)p;     p += alignup((size_t)N_EDGES * 4);
    float*  gsum    = (float*)p;   p += alignup(NGRAPHS * CH * 4);

    hipMemsetAsync(bhist, 0, NBUCK * 4, stream);
    hipMemsetAsync(gsum, 0, NGRAPHS * CH * 4, stream);

    bhist_k<<<F1BLOCKS, 256, 0, stream>>>(dst, bhist);
    bscan_k<<<1, 512, 0, stream>>>(bhist, bbase, bcur);
    bucket_scatter_k<<<F1BLOCKS, 256, 0, stream>>>(src, dst, bcur, stage);
    bucket_build_k<<<NBUCK, 256, 0, stream>>>(stage, bbase, offsets, dis, csr);
    boundary_k<<<(N_NODES + 255) / 256, 256, 0, stream>>>(batch, gstart);
    prep_w_k<<<3, 256, 0, stream>>>(W0, W1, W2, Wt0, Wt1, Wt2);

    const int GB = (N_NODES + GR - 1) / GR;   // 782 gemm blocks
    const int AB = (N_NODES + 3) / 4;         // agg blocks per pass

    // layer 0: x (f32) -> hsbuf -> bufA
    gemm_mfma_k<true><<<GB, 256, 0, stream>>>(x, Wt0, dis, hsbuf);
    agg_k<<<dim3(AB, NSLAB), 256, 0, stream>>>(hsbuf, offsets, csr, dis, b0, bufA);
    // layer 1
    gemm_mfma_k<false><<<GB, 256, 0, stream>>>(bufA, Wt1, dis, hsbuf);
    agg_k<<<dim3(AB, NSLAB), 256, 0, stream>>>(hsbuf, offsets, csr, dis, b1, bufA);
    // layer 2
    gemm_mfma_k<false><<<GB, 256, 0, stream>>>(bufA, Wt2, dis, hsbuf);
    agg_k<<<dim3(AB, NSLAB), 256, 0, stream>>>(hsbuf, offsets, csr, dis, b2, bufA);

    pool_k<<<dim3(8, NGRAPHS), 256, 0, stream>>>(bufA, gstart, gsum);
    head_k<<<1, 128, 0, stream>>>(gsum, gstart, Wlin, blin, out);
}

// Round 10
// 408.241 us; speedup vs baseline: 1.1023x; 1.1023x over previous
//
#include <hip/hip_runtime.h>
#include <hip/hip_fp16.h>

#define N_NODES   50000
#define N_EDGES   1600000
#define CH        128
#define OUTC      2
#define NGRAPHS   64

#define NBUCK     391          // ceil(N_NODES / 128)
#define EPB       4096         // edges per block in edge-parallel kernels
#define F1BLOCKS  391          // ceil(N_EDGES / EPB)
#define PADSLOT   8192         // fixed padded-csr slot per bucket (max ~6400 needed)
#define DUMMY16   ((unsigned short)N_NODES)

#define GR        64           // gemm rows per block
#define NSLAB     4            // channel slabs (32 ch each)
#define SLABROWS  (N_NODES + 1)                   // +1 zero row for dummy gathers
#define SLABHALF  ((size_t)SLABROWS * 32)         // _Float16 per slab
#define SLABH2    ((size_t)SLABROWS * 16)         // half2 per slab
#define SLABBYTE  ((size_t)SLABROWS * 64)         // bytes per slab

using f16x8 = __attribute__((ext_vector_type(8))) _Float16;
using f32x4 = __attribute__((ext_vector_type(4))) float;

// ---------------- CSR build (bucket-level, no per-node global atomics) ----------------

__global__ __launch_bounds__(256) void bhist_k(const int* __restrict__ dst,
                                               int* __restrict__ bhist) {
    __shared__ int hist[NBUCK];
    const int tid = threadIdx.x;
    const int e0  = blockIdx.x * EPB;
    const int nE  = min(EPB, N_EDGES - e0);
    for (int i = tid; i < NBUCK; i += 256) hist[i] = 0;
    __syncthreads();
    for (int i = tid; i < nE; i += 256) atomicAdd(&hist[dst[e0 + i] >> 7], 1);
    __syncthreads();
    for (int i = tid; i < NBUCK; i += 256) if (hist[i]) atomicAdd(&bhist[i], hist[i]);
}

__global__ __launch_bounds__(512) void bscan_k(const int* __restrict__ bhist,
                                               int* __restrict__ bbase,
                                               int* __restrict__ bcur) {
    const int t = threadIdx.x, lane = t & 63, w = t >> 6;
    int v = (t < NBUCK) ? bhist[t] : 0;
    int iv = v;
    #pragma unroll
    for (int d = 1; d < 64; d <<= 1) {
        int o = __shfl_up(iv, d, 64);
        if (lane >= d) iv += o;
    }
    __shared__ int ws[8];
    if (lane == 63) ws[w] = iv;
    __syncthreads();
    int add = 0;
    #pragma unroll
    for (int k = 0; k < 8; k++) if (k < w) add += ws[k];
    int excl = add + iv - v;
    if (t < NBUCK) { bbase[t] = excl; bcur[t] = excl; }
    if (t == NBUCK - 1) bbase[NBUCK] = excl + v;
}

// scatter packed (src | ldst<<16) into bucket-contiguous staging
__global__ __launch_bounds__(256) void bucket_scatter_k(const int* __restrict__ src,
                                                        const int* __restrict__ dst,
                                                        int* __restrict__ bucketCursor,
                                                        int* __restrict__ stage) {
    __shared__ int hist[NBUCK];
    __shared__ int cur[NBUCK];
    __shared__ int gbase[NBUCK];
    const int tid = threadIdx.x;
    const int e0  = blockIdx.x * EPB;
    const int nE  = min(EPB, N_EDGES - e0);

    for (int i = tid; i < NBUCK; i += 256) hist[i] = 0;
    __syncthreads();
    for (int i = tid; i < nE; i += 256) {
        int d = dst[e0 + i];
        atomicAdd(&hist[d >> 7], 1);
    }
    __syncthreads();
    for (int i = tid; i < NBUCK; i += 256) {
        int h = hist[i];
        gbase[i] = h ? atomicAdd(&bucketCursor[i], h) : 0;
        cur[i] = 0;
    }
    __syncthreads();
    for (int i = tid; i < nE; i += 256) {
        int d = dst[e0 + i];
        int s = src[e0 + i];
        int b = d >> 7;
        int pos = gbase[b] + atomicAdd(&cur[b], 1);
        stage[pos] = s | ((d & 127) << 16);
    }
}

// per-bucket: padded per-node offsets, dis, ordered+padded u16 csr (dummy = zero row)
__global__ __launch_bounds__(256) void bucket_build_k(const int* __restrict__ stage,
                                                      const int* __restrict__ bbase,
                                                      int* __restrict__ offsets,
                                                      int* __restrict__ ecnt,
                                                      float* __restrict__ dis,
                                                      unsigned short* __restrict__ csr16) {
    __shared__ int lcnt[128];
    __shared__ int lcur[128];
    __shared__ int wtot[2];
    __shared__ int ptotS;
    __shared__ unsigned short loc[PADSLOT];
    const int tid    = threadIdx.x;
    const int b      = blockIdx.x;
    const int first  = b << 7;
    const int nNodes = min(128, N_NODES - first);
    const int base   = bbase[b];
    const int bsize  = bbase[b + 1] - base;
    const int pbase  = b * PADSLOT;

    if (tid < 128) lcnt[tid] = 0;
    __syncthreads();
    for (int i = tid; i < bsize; i += 256)
        atomicAdd(&lcnt[((unsigned)stage[base + i]) >> 16], 1);
    __syncthreads();

    // inclusive scan over padded counts pc = roundup(c,16), 128 threads (2 waves)
    int iv = 0, c = 0, pc = 0;
    if (tid < 128) {
        c  = lcnt[tid];
        pc = (c + 15) & ~15;
        iv = pc;
        #pragma unroll
        for (int d = 1; d < 64; d <<= 1) {
            int o = __shfl_up(iv, d, 64);
            if ((tid & 63) >= d) iv += o;
        }
        if ((tid & 63) == 63) wtot[tid >> 6] = iv;
    }
    __syncthreads();
    if (tid < 128) {
        int add  = (tid >= 64) ? wtot[0] : 0;
        int excl = add + iv - pc;
        lcur[tid] = excl;
        if (tid < nNodes) {
            offsets[first + tid] = pbase + excl;
            ecnt[first + tid]    = c;
            dis[first + tid]     = rsqrtf((float)(c + 1));
        }
        if (tid == 127) ptotS = wtot[0] + wtot[1];
    }
    __syncthreads();
    const int ptot = min(ptotS, PADSLOT);

    for (int i = tid; i < ptot; i += 256) loc[i] = DUMMY16;
    __syncthreads();
    for (int i = tid; i < bsize; i += 256) {
        int sd  = stage[base + i];
        int pos = atomicAdd(&lcur[((unsigned)sd) >> 16], 1);
        loc[pos] = (unsigned short)(sd & 0xFFFF);
    }
    __syncthreads();
    for (int i = tid; i < ptot; i += 256) csr16[pbase + i] = loc[i];
}

// ---------------- graph ranges from sorted batch ----------------
__global__ __launch_bounds__(256) void boundary_k(const int* __restrict__ batch,
                                                  int* __restrict__ gstart) {
    int i = blockIdx.x * 256 + threadIdx.x;
    if (i >= N_NODES) return;
    int bc = batch[i];
    if (i == 0) {
        for (int g = 0; g <= bc; g++) gstart[g] = 0;
    } else {
        int bp = batch[i - 1];
        for (int g = bp + 1; g <= bc; g++) gstart[g] = i;
    }
    if (i == N_NODES - 1) {
        for (int g = bc + 1; g <= NGRAPHS; g++) gstart[g] = N_NODES;
    }
}

// ---------------- prep: W -> fp16 transpose; zero dummy rows of hsbuf ----------------
__global__ __launch_bounds__(256) void prep_w_k(const float* __restrict__ W0,
                                                const float* __restrict__ W1,
                                                const float* __restrict__ W2,
                                                __half* __restrict__ T0,
                                                __half* __restrict__ T1,
                                                __half* __restrict__ T2,
                                                __half* __restrict__ hsbuf) {
    if (blockIdx.x == 3) {
        // zero the 4 dummy rows (row N_NODES of each slab)
        int t = threadIdx.x;
        if (t < 128) {
            int q = t >> 5, i = t & 31;
            ((_Float16*)hsbuf)[(size_t)q * SLABHALF + (size_t)N_NODES * 32 + i] = (_Float16)0.f;
        }
        return;
    }
    const float* W = (blockIdx.x == 0) ? W0 : (blockIdx.x == 1) ? W1 : W2;
    __half* Wt     = (blockIdx.x == 0) ? T0 : (blockIdx.x == 1) ? T1 : T2;
    for (int i = threadIdx.x; i < CH * CH; i += 256) {
        int k = i >> 7, c = i & 127;
        Wt[c * CH + k] = __float2half(W[i]);
    }
}

// ---------------- MFMA GEMM: hs = (h @ W) * dis[row], fp16 slab-layout out ----------------
template <bool F32IN>
__global__ __launch_bounds__(256) void gemm_mfma_k(const void* __restrict__ hin,
                                                   const __half* __restrict__ Wt,
                                                   const float* __restrict__ dis,
                                                   __half* __restrict__ out) {
    __shared__ _Float16 Hl[GR][136];    // 17.4 KB
    __shared__ _Float16 Wl[CH][136];    // 34.8 KB
    const int tid = threadIdx.x;
    const int rowBase = blockIdx.x * GR;

    // stage Wt: thread -> col c = tid>>1, half q = tid&1 (8 x 16B)
    {
        const int c = tid >> 1, q = tid & 1;
        #pragma unroll
        for (int i = 0; i < 8; i++)
            *(f16x8*)&Wl[c][q * 64 + i * 8] =
                *(const f16x8*)&Wt[c * CH + q * 64 + i * 8];
    }
    // stage H: thread -> row r = tid>>2, quarter/slab q = tid&3 (32 halfs)
    {
        const int r = tid >> 2, q = tid & 3;
        const int n = rowBase + r;
        if constexpr (F32IN) {
            const float* h = (const float*)hin;
            #pragma unroll
            for (int i = 0; i < 8; i++) {
                float4 v = make_float4(0.f, 0.f, 0.f, 0.f);
                if (n < N_NODES) v = *(const float4*)&h[(size_t)n * CH + q * 32 + i * 4];
                *(__half2*)&Hl[r][q * 32 + i * 4]     = __floats2half2_rn(v.x, v.y);
                *(__half2*)&Hl[r][q * 32 + i * 4 + 2] = __floats2half2_rn(v.z, v.w);
            }
        } else {
            const _Float16* h = (const _Float16*)hin + (size_t)q * SLABHALF;
            #pragma unroll
            for (int i = 0; i < 4; i++) {
                f16x8 v = {};
                if (n < N_NODES) v = *(const f16x8*)&h[(size_t)n * 32 + i * 8];
                *(f16x8*)&Hl[r][q * 32 + i * 8] = v;
            }
        }
    }
    __syncthreads();

    const int w = tid >> 6, lane = tid & 63;
    const int l15 = lane & 15, kg = lane >> 4;

    f32x4 acc[8];
    #pragma unroll
    for (int t = 0; t < 8; t++) acc[t] = (f32x4){0.f, 0.f, 0.f, 0.f};

    #pragma unroll
    for (int kt = 0; kt < 4; kt++) {
        f16x8 a = *(f16x8*)&Hl[w * 16 + l15][kt * 32 + kg * 8];
        #pragma unroll
        for (int t = 0; t < 8; t++) {
            f16x8 b = *(f16x8*)&Wl[t * 16 + l15][kt * 32 + kg * 8];
            acc[t] = __builtin_amdgcn_mfma_f32_16x16x32_f16(a, b, acc[t], 0, 0, 0);
        }
    }
    __syncthreads();   // all waves done reading Hl

    // write scaled C into Hl (fp16), rows are wave-private
    #pragma unroll
    for (int r = 0; r < 4; r++) {
        const int lrow = w * 16 + kg * 4 + r;
        const int n = rowBase + lrow;
        const float s = (n < N_NODES) ? dis[n] : 0.f;
        #pragma unroll
        for (int t = 0; t < 8; t++)
            Hl[lrow][t * 16 + l15] = (_Float16)(acc[t][r] * s);
    }
    __syncthreads();

    // coalesced stream-out to slab layout
    {
        const int r = tid >> 2, q = tid & 3;
        const int n = rowBase + r;
        if (n < N_NODES) {
            _Float16* o = (_Float16*)out + (size_t)q * SLABHALF;
            #pragma unroll
            for (int i = 0; i < 4; i++)
                *(f16x8*)&o[(size_t)n * 32 + i * 8] = *(f16x8*)&Hl[r][q * 32 + i * 8];
        }
    }
}

// ---------------- Aggregate (channel-split, padded csr): slab-resident gather ----------------
// wave = 1 node x 1 slab; lane: eg = lane>>4 (edge group), d = lane&15 (half2 in 64B row).
// Inner 16 edges: 1 ushort4 index load + 4 unconditional gathers (dummy -> zero row).
__global__ __launch_bounds__(256) void agg_k(const __half* __restrict__ hs,
                                             const int* __restrict__ offsets,
                                             const int* __restrict__ ecnt,
                                             const unsigned short* __restrict__ csr16,
                                             const float* __restrict__ dis,
                                             const float* __restrict__ bias,
                                             __half* __restrict__ out) {
    const int p    = blockIdx.y;               // slab 0..3
    const int wid  = threadIdx.x >> 6;
    const int lane = threadIdx.x & 63;
    const int n = blockIdx.x * 4 + wid;
    if (n >= N_NODES) return;
    const int eg = lane >> 4;
    const int d4 = (lane & 15) << 2;           // byte offset of half2 within row
    const char* sb = (const char*)hs + (size_t)p * SLABBYTE;

    float2 acc = make_float2(0.f, 0.f);
    if (eg == 0) {
        float2 v = __half22float2(*(const __half2*)(sb + (size_t)n * 64 + d4));
        acc.x = v.x; acc.y = v.y;              // self-loop once
    }

    const int beg  = offsets[n];
    const int cnt  = ecnt[n];
    const int pcnt = (cnt + 15) & ~15;

    for (int e = 0; e < pcnt; e += 16) {
        ushort4 ix = *(const ushort4*)&csr16[beg + e + eg * 4];
        unsigned o0 = ((unsigned)ix.x) << 6;
        unsigned o1 = ((unsigned)ix.y) << 6;
        unsigned o2 = ((unsigned)ix.z) << 6;
        unsigned o3 = ((unsigned)ix.w) << 6;
        __half2 v0 = *(const __half2*)(sb + o0 + d4);
        __half2 v1 = *(const __half2*)(sb + o1 + d4);
        __half2 v2 = *(const __half2*)(sb + o2 + d4);
        __half2 v3 = *(const __half2*)(sb + o3 + d4);
        float2 f0 = __half22float2(v0);
        float2 f1 = __half22float2(v1);
        float2 f2 = __half22float2(v2);
        float2 f3 = __half22float2(v3);
        acc.x += (f0.x + f1.x) + (f2.x + f3.x);
        acc.y += (f0.y + f1.y) + (f2.y + f3.y);
    }

    // combine the 4 edge-groups (channels match across groups)
    acc.x += __shfl_xor(acc.x, 16); acc.y += __shfl_xor(acc.y, 16);
    acc.x += __shfl_xor(acc.x, 32); acc.y += __shfl_xor(acc.y, 32);

    if (eg == 0) {
        const float dn = dis[n];
        float2 b = *(const float2*)&bias[p * 32 + (lane & 15) * 2];
        float rx = fmaxf(dn * acc.x + b.x, 0.f);
        float ry = fmaxf(dn * acc.y + b.y, 0.f);
        ((__half2*)out)[(size_t)p * SLABH2 + (size_t)n * 16 + (lane & 15)] =
            __floats2half2_rn(rx, ry);
    }
}

// ---------------- Global mean pool over fp16 slab h: grid (8 chunks, 64 graphs) ----------------
__global__ __launch_bounds__(256) void pool_k(const __half* __restrict__ h,
                                              const int* __restrict__ gstart,
                                              float* __restrict__ gsum) {
    const int g   = blockIdx.y;
    const int s   = blockIdx.x;        // chunk 0..7
    const int tid = threadIdx.x;
    const int r   = tid >> 5;          // 0..7 row slot
    const int cq  = tid & 31;          // channel quad: channels cq*4..+3
    const __half2* slab = (const __half2*)h + (size_t)(cq >> 3) * SLABH2;
    const int dw = (cq & 7) * 2;
    const int start = gstart[g], end = gstart[g + 1];
    const int len   = end - start;
    const int chunk = (len + 7) >> 3;
    const int lo = start + s * chunk;
    const int hi = min(lo + chunk, end);

    float4 acc = make_float4(0.f, 0.f, 0.f, 0.f);
    for (int row = lo + r; row < hi; row += 8) {
        float2 a = __half22float2(slab[(size_t)row * 16 + dw]);
        float2 b = __half22float2(slab[(size_t)row * 16 + dw + 1]);
        acc.x += a.x; acc.y += a.y; acc.z += b.x; acc.w += b.y;
    }

    __shared__ float4 red[256];
    red[tid] = acc;
    __syncthreads();
    #pragma unroll
    for (int off = 4; off >= 1; off >>= 1) {
        if (r < off) {
            float4 o = red[tid + off * 32];
            red[tid].x += o.x; red[tid].y += o.y;
            red[tid].z += o.z; red[tid].w += o.w;
        }
        __syncthreads();
    }
    if (r == 0) {
        float4 v = red[tid];
        atomicAdd(&gsum[g * CH + cq * 4 + 0], v.x);
        atomicAdd(&gsum[g * CH + cq * 4 + 1], v.y);
        atomicAdd(&gsum[g * CH + cq * 4 + 2], v.z);
        atomicAdd(&gsum[g * CH + cq * 4 + 3], v.w);
    }
}

// ---------------- Head ----------------
__global__ __launch_bounds__(128) void head_k(const float* __restrict__ gsum,
                                              const int* __restrict__ gstart,
                                              const float* __restrict__ Wlin,
                                              const float* __restrict__ blin,
                                              float* __restrict__ out) {
    const int t = threadIdx.x;      // 0..127
    const int g = t >> 1;
    const int o = t & 1;
    float cnt = (float)max(gstart[g + 1] - gstart[g], 1);
    float s = 0.f;
    for (int ci = 0; ci < CH; ci++) s += gsum[g * CH + ci] * Wlin[ci * OUTC + o];
    out[g * OUTC + o] = s / cnt + blin[o];
}

// ---------------- launch ----------------

static inline size_t alignup(size_t x) { return (x + 255) & ~(size_t)255; }

extern "C" void kernel_launch(void* const* d_in, const int* in_sizes, int n_in,
                              void* d_out, int out_size, void* d_ws, size_t ws_size,
                              hipStream_t stream) {
    const float* x     = (const float*)d_in[0];
    const int*   eidx  = (const int*)d_in[1];
    const int*   batch = (const int*)d_in[2];
    const float* W0    = (const float*)d_in[3];
    const float* b0    = (const float*)d_in[4];
    const float* W1    = (const float*)d_in[5];
    const float* b1    = (const float*)d_in[6];
    const float* W2    = (const float*)d_in[7];
    const float* b2    = (const float*)d_in[8];
    const float* Wlin  = (const float*)d_in[9];
    const float* blin  = (const float*)d_in[10];
    float* out = (float*)d_out;

    const int* src = eidx;
    const int* dst = eidx + N_EDGES;

    char* p = (char*)d_ws;
    int*    offsets = (int*)p;     p += alignup(N_NODES * 4);
    int*    ecnt    = (int*)p;     p += alignup(N_NODES * 4);
    float*  dis     = (float*)p;   p += alignup(N_NODES * 4);
    int*    bhist   = (int*)p;     p += alignup(NBUCK * 4);
    int*    bbase   = (int*)p;     p += alignup((NBUCK + 1) * 4);
    int*    bcur    = (int*)p;     p += alignup(NBUCK * 4);
    int*    gstart  = (int*)p;     p += alignup((NGRAPHS + 1) * 4);
    unsigned short* csr16 = (unsigned short*)p; p += alignup((size_t)NBUCK * PADSLOT * 2);
    __half* Wt0     = (__half*)p;  p += alignup(CH * CH * 2);
    __half* Wt1     = (__half*)p;  p += alignup(CH * CH * 2);
    __half* Wt2     = (__half*)p;  p += alignup(CH * CH * 2);
    __half* bufA    = (__half*)p;  p += alignup(SLABHALF * NSLAB * 2);
    __half* hsbuf   = (__half*)p;  p += alignup(SLABHALF * NSLAB * 2);
    int*    stage   = (int*)p;     p += alignup((size_t)N_EDGES * 4);
    float*  gsum    = (float*)p;   p += alignup(NGRAPHS * CH * 4);

    hipMemsetAsync(bhist, 0, NBUCK * 4, stream);
    hipMemsetAsync(gsum, 0, NGRAPHS * CH * 4, stream);

    bhist_k<<<F1BLOCKS, 256, 0, stream>>>(dst, bhist);
    bscan_k<<<1, 512, 0, stream>>>(bhist, bbase, bcur);
    bucket_scatter_k<<<F1BLOCKS, 256, 0, stream>>>(src, dst, bcur, stage);
    bucket_build_k<<<NBUCK, 256, 0, stream>>>(stage, bbase, offsets, ecnt, dis, csr16);
    boundary_k<<<(N_NODES + 255) / 256, 256, 0, stream>>>(batch, gstart);
    prep_w_k<<<4, 256, 0, stream>>>(W0, W1, W2, Wt0, Wt1, Wt2, hsbuf);

    const int GB = (N_NODES + GR - 1) / GR;   // 782 gemm blocks
    const int AB = (N_NODES + 3) / 4;         // agg blocks per slab

    // layer 0: x (f32) -> hsbuf -> bufA
    gemm_mfma_k<true><<<GB, 256, 0, stream>>>(x, Wt0, dis, hsbuf);
    agg_k<<<dim3(AB, NSLAB), 256, 0, stream>>>(hsbuf, offsets, ecnt, csr16, dis, b0, bufA);
    // layer 1
    gemm_mfma_k<false><<<GB, 256, 0, stream>>>(bufA, Wt1, dis, hsbuf);
    agg_k<<<dim3(AB, NSLAB), 256, 0, stream>>>(hsbuf, offsets, ecnt, csr16, dis, b1, bufA);
    // layer 2
    gemm_mfma_k<false><<<GB, 256, 0, stream>>>(bufA, Wt2, dis, hsbuf);
    agg_k<<<dim3(AB, NSLAB), 256, 0, stream>>>(hsbuf, offsets, ecnt, csr16, dis, b2, bufA);

    pool_k<<<dim3(8, NGRAPHS), 256, 0, stream>>>(bufA, gstart, gsum);
    head_k<<<1, 128, 0, stream>>>(gsum, gstart, Wlin, blin, out);
}

// Round 11
// 280.906 us; speedup vs baseline: 1.6020x; 1.4533x over previous
//
#include <hip/hip_runtime.h>
#include <hip/hip_fp16.h>

#define N_NODES   50000
#define N_EDGES   1600000
#define CH        128
#define OUTC      2
#define NGRAPHS   64

#define NBUCK     391          // ceil(N_NODES / 128)
#define EPB       4096         // edges per block in edge-parallel kernels
#define F1BLOCKS  391          // ceil(N_EDGES / EPB)
#define PADSLOT   8192         // fixed stage/csr slot per bucket (max fill ~4500)
#define DUMMY16   ((unsigned short)50000)

#define GR        64           // gemm rows per block

using f16x8 = __attribute__((ext_vector_type(8))) _Float16;
using f32x4 = __attribute__((ext_vector_type(4))) float;

// ---------------- init: bucket cursors to static slots; zero dummy row of hsbuf ----------------
__global__ __launch_bounds__(512) void init_k(int* __restrict__ bcur,
                                              __half* __restrict__ hsbuf) {
    int t = threadIdx.x;
    if (t < NBUCK) bcur[t] = t * PADSLOT;
    if (t < 64) ((__half2*)hsbuf)[(size_t)N_NODES * 64 + t] = __floats2half2_rn(0.f, 0.f);
}

// ---------------- scatter packed (src | ldst<<16) into static bucket slots ----------------
__global__ __launch_bounds__(256) void bucket_scatter_k(const int* __restrict__ src,
                                                        const int* __restrict__ dst,
                                                        int* __restrict__ bucketCursor,
                                                        int* __restrict__ stage) {
    __shared__ int hist[NBUCK];
    __shared__ int cur[NBUCK];
    __shared__ int gbase[NBUCK];
    const int tid = threadIdx.x;
    const int e0  = blockIdx.x * EPB;
    const int nE  = min(EPB, N_EDGES - e0);

    for (int i = tid; i < NBUCK; i += 256) hist[i] = 0;
    __syncthreads();
    for (int i = tid; i < nE; i += 256) {
        int d = dst[e0 + i];
        atomicAdd(&hist[d >> 7], 1);
    }
    __syncthreads();
    for (int i = tid; i < NBUCK; i += 256) {
        int h = hist[i];
        gbase[i] = h ? atomicAdd(&bucketCursor[i], h) : 0;
        cur[i] = 0;
    }
    __syncthreads();
    for (int i = tid; i < nE; i += 256) {
        int d = dst[e0 + i];
        int s = src[e0 + i];
        int b = d >> 7;
        int pos = gbase[b] + atomicAdd(&cur[b], 1);
        stage[pos] = s | ((d & 127) << 16);
    }
}

// ---------------- per-bucket: offsets/ecnt/dis + ordered u16 csr padded to mult-of-4 ----------------
__global__ __launch_bounds__(256) void bucket_build_k(const int* __restrict__ stage,
                                                      const int* __restrict__ bcur,
                                                      int* __restrict__ offsets,
                                                      int* __restrict__ ecnt,
                                                      float* __restrict__ dis,
                                                      unsigned short* __restrict__ csr16) {
    __shared__ int lcnt[128];
    __shared__ int lcur[128];
    __shared__ int wtot[2];
    __shared__ int ptotS;
    __shared__ unsigned short loc[PADSLOT];
    const int tid    = threadIdx.x;
    const int b      = blockIdx.x;
    const int first  = b << 7;
    const int nNodes = min(128, N_NODES - first);
    const int pbase  = b * PADSLOT;
    const int bsize  = bcur[b] - pbase;

    if (tid < 128) lcnt[tid] = 0;
    __syncthreads();
    for (int i = tid; i < bsize; i += 256)
        atomicAdd(&lcnt[((unsigned)stage[pbase + i]) >> 16], 1);
    __syncthreads();

    // inclusive scan over padded counts pc = roundup(c,4), 128 threads (2 waves)
    int iv = 0, c = 0, pc = 0;
    if (tid < 128) {
        c  = lcnt[tid];
        pc = (c + 3) & ~3;
        iv = pc;
        #pragma unroll
        for (int d = 1; d < 64; d <<= 1) {
            int o = __shfl_up(iv, d, 64);
            if ((tid & 63) >= d) iv += o;
        }
        if ((tid & 63) == 63) wtot[tid >> 6] = iv;
    }
    __syncthreads();
    if (tid < 128) {
        int add  = (tid >= 64) ? wtot[0] : 0;
        int excl = add + iv - pc;
        lcur[tid] = excl;
        if (tid < nNodes) {
            offsets[first + tid] = pbase + excl;
            ecnt[first + tid]    = c;
            dis[first + tid]     = rsqrtf((float)(c + 1));
        }
        if (tid == 127) ptotS = wtot[0] + wtot[1];
    }
    __syncthreads();
    const int ptot = min(ptotS, PADSLOT);

    for (int i = tid; i < ptot; i += 256) loc[i] = DUMMY16;
    __syncthreads();
    for (int i = tid; i < bsize; i += 256) {
        int sd  = stage[pbase + i];
        int pos = atomicAdd(&lcur[((unsigned)sd) >> 16], 1);
        loc[pos] = (unsigned short)(sd & 0xFFFF);
    }
    __syncthreads();
    for (int i = tid; i < ptot; i += 256) csr16[pbase + i] = loc[i];
}

// ---------------- graph ranges from sorted batch ----------------
__global__ __launch_bounds__(256) void boundary_k(const int* __restrict__ batch,
                                                  int* __restrict__ gstart) {
    int i = blockIdx.x * 256 + threadIdx.x;
    if (i >= N_NODES) return;
    int bc = batch[i];
    if (i == 0) {
        for (int g = 0; g <= bc; g++) gstart[g] = 0;
    } else {
        int bp = batch[i - 1];
        for (int g = bp + 1; g <= bc; g++) gstart[g] = i;
    }
    if (i == N_NODES - 1) {
        for (int g = bc + 1; g <= NGRAPHS; g++) gstart[g] = N_NODES;
    }
}

// ---------------- W -> fp16 transpose: Wt[c][k] = W[k][c] ----------------
__global__ __launch_bounds__(256) void prep_w_k(const float* __restrict__ W0,
                                                const float* __restrict__ W1,
                                                const float* __restrict__ W2,
                                                __half* __restrict__ T0,
                                                __half* __restrict__ T1,
                                                __half* __restrict__ T2) {
    const float* W = (blockIdx.x == 0) ? W0 : (blockIdx.x == 1) ? W1 : W2;
    __half* Wt     = (blockIdx.x == 0) ? T0 : (blockIdx.x == 1) ? T1 : T2;
    for (int i = threadIdx.x; i < CH * CH; i += 256) {
        int k = i >> 7, c = i & 127;
        Wt[c * CH + k] = __float2half(W[i]);
    }
}

// ---------------- MFMA GEMM: hs = (h @ W) * dis[row], fp16 flat [N][128] out ----------------
template <bool F32IN>
__global__ __launch_bounds__(256) void gemm_mfma_k(const void* __restrict__ hin,
                                                   const __half* __restrict__ Wt,
                                                   const float* __restrict__ dis,
                                                   __half* __restrict__ out) {
    __shared__ _Float16 Hl[GR][136];    // 17.4 KB
    __shared__ _Float16 Wl[CH][136];    // 34.8 KB
    const int tid = threadIdx.x;
    const int rowBase = blockIdx.x * GR;

    // stage Wt: thread -> col c = tid>>1, half q = tid&1 (8 x 16B)
    {
        const int c = tid >> 1, q = tid & 1;
        #pragma unroll
        for (int i = 0; i < 8; i++)
            *(f16x8*)&Wl[c][q * 64 + i * 8] =
                *(const f16x8*)&Wt[c * CH + q * 64 + i * 8];
    }
    // stage H: thread -> row r = tid>>2, quarter q = tid&3 (32 halfs)
    {
        const int r = tid >> 2, q = tid & 3;
        const int n = rowBase + r;
        if constexpr (F32IN) {
            const float* h = (const float*)hin;
            #pragma unroll
            for (int i = 0; i < 8; i++) {
                float4 v = make_float4(0.f, 0.f, 0.f, 0.f);
                if (n < N_NODES) v = *(const float4*)&h[(size_t)n * CH + q * 32 + i * 4];
                *(__half2*)&Hl[r][q * 32 + i * 4]     = __floats2half2_rn(v.x, v.y);
                *(__half2*)&Hl[r][q * 32 + i * 4 + 2] = __floats2half2_rn(v.z, v.w);
            }
        } else {
            const _Float16* h = (const _Float16*)hin;
            #pragma unroll
            for (int i = 0; i < 4; i++) {
                f16x8 v = {};
                if (n < N_NODES) v = *(const f16x8*)&h[(size_t)n * CH + q * 32 + i * 8];
                *(f16x8*)&Hl[r][q * 32 + i * 8] = v;
            }
        }
    }
    __syncthreads();

    const int w = tid >> 6, lane = tid & 63;
    const int l15 = lane & 15, kg = lane >> 4;

    f32x4 acc[8];
    #pragma unroll
    for (int t = 0; t < 8; t++) acc[t] = (f32x4){0.f, 0.f, 0.f, 0.f};

    #pragma unroll
    for (int kt = 0; kt < 4; kt++) {
        f16x8 a = *(f16x8*)&Hl[w * 16 + l15][kt * 32 + kg * 8];
        #pragma unroll
        for (int t = 0; t < 8; t++) {
            f16x8 b = *(f16x8*)&Wl[t * 16 + l15][kt * 32 + kg * 8];
            acc[t] = __builtin_amdgcn_mfma_f32_16x16x32_f16(a, b, acc[t], 0, 0, 0);
        }
    }
    __syncthreads();   // all waves done reading Hl

    // write scaled C into Hl (fp16), rows are wave-private
    #pragma unroll
    for (int r = 0; r < 4; r++) {
        const int lrow = w * 16 + kg * 4 + r;
        const int n = rowBase + lrow;
        const float s = (n < N_NODES) ? dis[n] : 0.f;
        #pragma unroll
        for (int t = 0; t < 8; t++)
            Hl[lrow][t * 16 + l15] = (_Float16)(acc[t][r] * s);
    }
    __syncthreads();

    // coalesced stream-out
    {
        const int r = tid >> 2, q = tid & 3;
        const int n = rowBase + r;
        if (n < N_NODES) {
            #pragma unroll
            for (int i = 0; i < 4; i++)
                *(f16x8*)&((_Float16*)out)[(size_t)n * CH + q * 32 + i * 8] =
                    *(f16x8*)&Hl[r][q * 32 + i * 8];
        }
    }
}

// ---------------- Aggregate v3: h[n] = relu(dis[n]*(sum_e hs[src_e] + hs[n]) + b) ----------------
// wave = 1 node; 16 lanes/edge x 16B (dwordx4) = 4 edges/instr; indices preloaded
// one-per-lane and broadcast via shfl; csr padded to mult-of-4 with DUMMY -> zero row.
__global__ __launch_bounds__(256) void agg_k(const __half* __restrict__ hs,
                                             const int* __restrict__ offsets,
                                             const int* __restrict__ ecnt,
                                             const unsigned short* __restrict__ csr16,
                                             const float* __restrict__ dis,
                                             const float* __restrict__ bias,
                                             __half* __restrict__ out) {
    const int wid  = threadIdx.x >> 6;
    const int lane = threadIdx.x & 63;
    const int n = blockIdx.x * 4 + wid;
    if (n >= N_NODES) return;
    const int g   = lane >> 4;            // edge slot 0..3
    const int seg = lane & 15;            // 16B segment of the 256B row
    const char* base = (const char*)hs;

    const int beg = offsets[n];
    const int cnt = ecnt[n];

    int myidx = DUMMY16;
    if (lane < cnt) myidx = (int)csr16[beg + lane];   // coalesced 128B

    float acc[8];
    #pragma unroll
    for (int i = 0; i < 8; i++) acc[i] = 0.f;

    if (g == 0) {  // self-loop term, counted once
        f16x8 v = *(const f16x8*)(base + (size_t)n * 256 + seg * 16);
        #pragma unroll
        for (int i = 0; i < 8; i++) acc[i] += (float)v[i];
    }

    const int pcnt  = (cnt + 3) & ~3;
    const int mainc = min(pcnt, 64);
    for (int e = 0; e < mainc; e += 4) {
        int idx = __shfl(myidx, e + g);
        f16x8 v = *(const f16x8*)(base + (size_t)idx * 256 + seg * 16);
        #pragma unroll
        for (int i = 0; i < 8; i++) acc[i] += (float)v[i];
    }
    // rare tail: degree > 64
    for (int e = 64; e < pcnt; e += 4) {
        int idx = (int)csr16[beg + e + g];
        f16x8 v = *(const f16x8*)(base + (size_t)idx * 256 + seg * 16);
        #pragma unroll
        for (int i = 0; i < 8; i++) acc[i] += (float)v[i];
    }

    // reduce across the 4 edge slots (same channels per seg)
    #pragma unroll
    for (int i = 0; i < 8; i++) {
        acc[i] += __shfl_xor(acc[i], 16);
        acc[i] += __shfl_xor(acc[i], 32);
    }

    if (g == 0) {
        const float dn = dis[n];
        float4 b0 = *(const float4*)&bias[seg * 8];
        float4 b1 = *(const float4*)&bias[seg * 8 + 4];
        f16x8 r;
        r[0] = (_Float16)fmaxf(dn * acc[0] + b0.x, 0.f);
        r[1] = (_Float16)fmaxf(dn * acc[1] + b0.y, 0.f);
        r[2] = (_Float16)fmaxf(dn * acc[2] + b0.z, 0.f);
        r[3] = (_Float16)fmaxf(dn * acc[3] + b0.w, 0.f);
        r[4] = (_Float16)fmaxf(dn * acc[4] + b1.x, 0.f);
        r[5] = (_Float16)fmaxf(dn * acc[5] + b1.y, 0.f);
        r[6] = (_Float16)fmaxf(dn * acc[6] + b1.z, 0.f);
        r[7] = (_Float16)fmaxf(dn * acc[7] + b1.w, 0.f);
        *(f16x8*)&((_Float16*)out)[(size_t)n * CH + seg * 8] = r;
    }
}

// ---------------- Global mean pool over fp16 flat h: grid (8 chunks, 64 graphs) ----------------
__global__ __launch_bounds__(256) void pool_k(const __half* __restrict__ h,
                                              const int* __restrict__ gstart,
                                              float* __restrict__ gsum) {
    const __half2* h2 = (const __half2*)h;
    const int g   = blockIdx.y;
    const int s   = blockIdx.x;        // chunk 0..7
    const int tid = threadIdx.x;
    const int r   = tid >> 5;          // 0..7 row slot
    const int cq  = tid & 31;          // channel quad
    const int start = gstart[g], end = gstart[g + 1];
    const int len   = end - start;
    const int chunk = (len + 7) >> 3;
    const int lo = start + s * chunk;
    const int hi = min(lo + chunk, end);

    float4 acc = make_float4(0.f, 0.f, 0.f, 0.f);
    for (int row = lo + r; row < hi; row += 8) {
        float2 a = __half22float2(h2[(size_t)row * 64 + cq * 2]);
        float2 b = __half22float2(h2[(size_t)row * 64 + cq * 2 + 1]);
        acc.x += a.x; acc.y += a.y; acc.z += b.x; acc.w += b.y;
    }

    __shared__ float4 red[256];
    red[tid] = acc;
    __syncthreads();
    #pragma unroll
    for (int off = 4; off >= 1; off >>= 1) {
        if (r < off) {
            float4 o = red[tid + off * 32];
            red[tid].x += o.x; red[tid].y += o.y;
            red[tid].z += o.z; red[tid].w += o.w;
        }
        __syncthreads();
    }
    if (r == 0) {
        float4 v = red[tid];
        atomicAdd(&gsum[g * CH + cq * 4 + 0], v.x);
        atomicAdd(&gsum[g * CH + cq * 4 + 1], v.y);
        atomicAdd(&gsum[g * CH + cq * 4 + 2], v.z);
        atomicAdd(&gsum[g * CH + cq * 4 + 3], v.w);
    }
}

// ---------------- Head ----------------
__global__ __launch_bounds__(128) void head_k(const float* __restrict__ gsum,
                                              const int* __restrict__ gstart,
                                              const float* __restrict__ Wlin,
                                              const float* __restrict__ blin,
                                              float* __restrict__ out) {
    const int t = threadIdx.x;      // 0..127
    const int g = t >> 1;
    const int o = t & 1;
    float cnt = (float)max(gstart[g + 1] - gstart[g], 1);
    float s = 0.f;
    for (int ci = 0; ci < CH; ci++) s += gsum[g * CH + ci] * Wlin[ci * OUTC + o];
    out[g * OUTC + o] = s / cnt + blin[o];
}

// ---------------- launch ----------------

static inline size_t alignup(size_t x) { return (x + 255) & ~(size_t)255; }

extern "C" void kernel_launch(void* const* d_in, const int* in_sizes, int n_in,
                              void* d_out, int out_size, void* d_ws, size_t ws_size,
                              hipStream_t stream) {
    const float* x     = (const float*)d_in[0];
    const int*   eidx  = (const int*)d_in[1];
    const int*   batch = (const int*)d_in[2];
    const float* W0    = (const float*)d_in[3];
    const float* b0    = (const float*)d_in[4];
    const float* W1    = (const float*)d_in[5];
    const float* b1    = (const float*)d_in[6];
    const float* W2    = (const float*)d_in[7];
    const float* b2    = (const float*)d_in[8];
    const float* Wlin  = (const float*)d_in[9];
    const float* blin  = (const float*)d_in[10];
    float* out = (float*)d_out;

    const int* src = eidx;
    const int* dst = eidx + N_EDGES;

    char* p = (char*)d_ws;
    int*    offsets = (int*)p;     p += alignup(N_NODES * 4);
    int*    ecnt    = (int*)p;     p += alignup(N_NODES * 4);
    float*  dis     = (float*)p;   p += alignup(N_NODES * 4);
    int*    bcur    = (int*)p;     p += alignup(NBUCK * 4);
    int*    gstart  = (int*)p;     p += alignup((NGRAPHS + 1) * 4);
    unsigned short* csr16 = (unsigned short*)p; p += alignup((size_t)NBUCK * PADSLOT * 2);
    __half* Wt0     = (__half*)p;  p += alignup(CH * CH * 2);
    __half* Wt1     = (__half*)p;  p += alignup(CH * CH * 2);
    __half* Wt2     = (__half*)p;  p += alignup(CH * CH * 2);
    __half* bufA    = (__half*)p;  p += alignup((size_t)N_NODES * CH * 2);
    __half* hsbuf   = (__half*)p;  p += alignup((size_t)(N_NODES + 1) * CH * 2);
    int*    stage   = (int*)p;     p += alignup((size_t)NBUCK * PADSLOT * 4);
    float*  gsum    = (float*)p;   p += alignup(NGRAPHS * CH * 4);

    hipMemsetAsync(gsum, 0, NGRAPHS * CH * 4, stream);

    init_k<<<1, 512, 0, stream>>>(bcur, hsbuf);
    bucket_scatter_k<<<F1BLOCKS, 256, 0, stream>>>(src, dst, bcur, stage);
    bucket_build_k<<<NBUCK, 256, 0, stream>>>(stage, bcur, offsets, ecnt, dis, csr16);
    boundary_k<<<(N_NODES + 255) / 256, 256, 0, stream>>>(batch, gstart);
    prep_w_k<<<3, 256, 0, stream>>>(W0, W1, W2, Wt0, Wt1, Wt2);

    const int GB = (N_NODES + GR - 1) / GR;   // 782 gemm blocks
    const int AB = (N_NODES + 3) / 4;         // agg blocks

    // layer 0: x (f32) -> hsbuf -> bufA
    gemm_mfma_k<true><<<GB, 256, 0, stream>>>(x, Wt0, dis, hsbuf);
    agg_k<<<AB, 256, 0, stream>>>(hsbuf, offsets, ecnt, csr16, dis, b0, bufA);
    // layer 1
    gemm_mfma_k<false><<<GB, 256, 0, stream>>>(bufA, Wt1, dis, hsbuf);
    agg_k<<<AB, 256, 0, stream>>>(hsbuf, offsets, ecnt, csr16, dis, b1, bufA);
    // layer 2
    gemm_mfma_k<false><<<GB, 256, 0, stream>>>(bufA, Wt2, dis, hsbuf);
    agg_k<<<AB, 256, 0, stream>>>(hsbuf, offsets, ecnt, csr16, dis, b2, bufA);

    pool_k<<<dim3(8, NGRAPHS), 256, 0, stream>>>(bufA, gstart, gsum);
    head_k<<<1, 128, 0, stream>>>(gsum, gstart, Wlin, blin, out);
}

// Round 12
// 272.899 us; speedup vs baseline: 1.6490x; 1.0293x over previous
//
#include <hip/hip_runtime.h>
#include <hip/hip_fp16.h>

#define N_NODES   50000
#define N_EDGES   1600000
#define CH        128
#define OUTC      2
#define NGRAPHS   64

#define NBUCK     391          // ceil(N_NODES / 128)
#define EPB       4096         // edges per block in edge-parallel kernels
#define F1BLOCKS  391          // ceil(N_EDGES / EPB)
#define PADSLOT   8192         // fixed stage/csr slot per bucket (max fill ~4500)
#define DUMMY16   ((unsigned short)50000)

#define GR        64           // gemm rows per block
#define BNDB      ((N_NODES + 255) / 256)   // 196 boundary blocks

using f16x8 = __attribute__((ext_vector_type(8))) _Float16;
using f32x4 = __attribute__((ext_vector_type(4))) float;

// ---------------- fused setup: boundary | W transpose | cursors/dummy/gsum ----------------
__global__ __launch_bounds__(256) void setup_k(const int* __restrict__ batch,
                                               int* __restrict__ gstart,
                                               const float* __restrict__ W0,
                                               const float* __restrict__ W1,
                                               const float* __restrict__ W2,
                                               __half* __restrict__ T0,
                                               __half* __restrict__ T1,
                                               __half* __restrict__ T2,
                                               int* __restrict__ bcur,
                                               __half* __restrict__ hsbuf,
                                               float* __restrict__ gsum) {
    const int b = blockIdx.x;
    const int tid = threadIdx.x;
    if (b < BNDB) {
        // graph ranges from sorted batch
        int i = b * 256 + tid;
        if (i >= N_NODES) return;
        int bc = batch[i];
        if (i == 0) {
            for (int g = 0; g <= bc; g++) gstart[g] = 0;
        } else {
            int bp = batch[i - 1];
            for (int g = bp + 1; g <= bc; g++) gstart[g] = i;
        }
        if (i == N_NODES - 1) {
            for (int g = bc + 1; g <= NGRAPHS; g++) gstart[g] = N_NODES;
        }
    } else if (b < BNDB + 3) {
        const int wi = b - BNDB;
        const float* W = (wi == 0) ? W0 : (wi == 1) ? W1 : W2;
        __half* Wt     = (wi == 0) ? T0 : (wi == 1) ? T1 : T2;
        for (int i = tid; i < CH * CH; i += 256) {
            int k = i >> 7, c = i & 127;
            Wt[c * CH + k] = __float2half(W[i]);
        }
    } else {
        for (int i = tid; i < NBUCK; i += 256) bcur[i] = i * PADSLOT;
        if (tid < 64) ((__half2*)hsbuf)[(size_t)N_NODES * 64 + tid] = __floats2half2_rn(0.f, 0.f);
        for (int i = tid; i < NGRAPHS * CH; i += 256) gsum[i] = 0.f;
    }
}

// ---------------- scatter packed (src | ldst<<16) into static bucket slots ----------------
__global__ __launch_bounds__(256) void bucket_scatter_k(const int* __restrict__ src,
                                                        const int* __restrict__ dst,
                                                        int* __restrict__ bucketCursor,
                                                        int* __restrict__ stage) {
    __shared__ int hist[NBUCK];
    __shared__ int cur[NBUCK];
    __shared__ int gbase[NBUCK];
    const int tid = threadIdx.x;
    const int e0  = blockIdx.x * EPB;
    const int nE  = min(EPB, N_EDGES - e0);

    for (int i = tid; i < NBUCK; i += 256) hist[i] = 0;
    __syncthreads();
    for (int i = tid; i < nE; i += 256) {
        int d = dst[e0 + i];
        atomicAdd(&hist[d >> 7], 1);
    }
    __syncthreads();
    for (int i = tid; i < NBUCK; i += 256) {
        int h = hist[i];
        gbase[i] = h ? atomicAdd(&bucketCursor[i], h) : 0;
        cur[i] = 0;
    }
    __syncthreads();
    for (int i = tid; i < nE; i += 256) {
        int d = dst[e0 + i];
        int s = src[e0 + i];
        int b = d >> 7;
        int pos = gbase[b] + atomicAdd(&cur[b], 1);
        stage[pos] = s | ((d & 127) << 16);
    }
}

// ---------------- per-bucket: offsets/ecnt/dis + ordered u16 csr padded to mult-of-4 ----------------
__global__ __launch_bounds__(256) void bucket_build_k(const int* __restrict__ stage,
                                                      const int* __restrict__ bcur,
                                                      int* __restrict__ offsets,
                                                      int* __restrict__ ecnt,
                                                      float* __restrict__ dis,
                                                      unsigned short* __restrict__ csr16) {
    __shared__ int lcnt[128];
    __shared__ int lcur[128];
    __shared__ int wtot[2];
    __shared__ int ptotS;
    __shared__ unsigned short loc[PADSLOT];
    const int tid    = threadIdx.x;
    const int b      = blockIdx.x;
    const int first  = b << 7;
    const int nNodes = min(128, N_NODES - first);
    const int pbase  = b * PADSLOT;
    const int bsize  = bcur[b] - pbase;

    if (tid < 128) lcnt[tid] = 0;
    __syncthreads();
    for (int i = tid; i < bsize; i += 256)
        atomicAdd(&lcnt[((unsigned)stage[pbase + i]) >> 16], 1);
    __syncthreads();

    // inclusive scan over padded counts pc = roundup(c,4), 128 threads (2 waves)
    int iv = 0, c = 0, pc = 0;
    if (tid < 128) {
        c  = lcnt[tid];
        pc = (c + 3) & ~3;
        iv = pc;
        #pragma unroll
        for (int d = 1; d < 64; d <<= 1) {
            int o = __shfl_up(iv, d, 64);
            if ((tid & 63) >= d) iv += o;
        }
        if ((tid & 63) == 63) wtot[tid >> 6] = iv;
    }
    __syncthreads();
    if (tid < 128) {
        int add  = (tid >= 64) ? wtot[0] : 0;
        int excl = add + iv - pc;
        lcur[tid] = excl;
        if (tid < nNodes) {
            offsets[first + tid] = pbase + excl;
            ecnt[first + tid]    = c;
            dis[first + tid]     = rsqrtf((float)(c + 1));
        }
        if (tid == 127) ptotS = wtot[0] + wtot[1];
    }
    __syncthreads();
    const int ptot = min(ptotS, PADSLOT);

    for (int i = tid; i < ptot; i += 256) loc[i] = DUMMY16;
    __syncthreads();
    for (int i = tid; i < bsize; i += 256) {
        int sd  = stage[pbase + i];
        int pos = atomicAdd(&lcur[((unsigned)sd) >> 16], 1);
        loc[pos] = (unsigned short)(sd & 0xFFFF);
    }
    __syncthreads();
    for (int i = tid; i < ptot; i += 256) csr16[pbase + i] = loc[i];
}

// ---------------- MFMA GEMM: hs = (h @ W) * dis[row], fp16 flat [N][128] out ----------------
// F32IN: stage H in LDS (with fp32->fp16 convert).  F16 path: A read direct from global.
template <bool F32IN>
__global__ __launch_bounds__(256) void gemm_mfma_k(const void* __restrict__ hin,
                                                   const __half* __restrict__ Wt,
                                                   const float* __restrict__ dis,
                                                   __half* __restrict__ out) {
    __shared__ _Float16 Hl[GR][136];    // 17.4 KB (input staging f32 path; C staging both)
    __shared__ _Float16 Wl[CH][136];    // 34.8 KB
    const int tid = threadIdx.x;
    const int rowBase = blockIdx.x * GR;

    // stage Wt: thread -> col c = tid>>1, half q = tid&1 (8 x 16B)
    {
        const int c = tid >> 1, q = tid & 1;
        #pragma unroll
        for (int i = 0; i < 8; i++)
            *(f16x8*)&Wl[c][q * 64 + i * 8] =
                *(const f16x8*)&Wt[c * CH + q * 64 + i * 8];
    }
    if constexpr (F32IN) {
        // stage H: thread -> row r = tid>>2, quarter q = tid&3 (32 halfs)
        const int r = tid >> 2, q = tid & 3;
        const int n = rowBase + r;
        const float* h = (const float*)hin;
        #pragma unroll
        for (int i = 0; i < 8; i++) {
            float4 v = make_float4(0.f, 0.f, 0.f, 0.f);
            if (n < N_NODES) v = *(const float4*)&h[(size_t)n * CH + q * 32 + i * 4];
            *(__half2*)&Hl[r][q * 32 + i * 4]     = __floats2half2_rn(v.x, v.y);
            *(__half2*)&Hl[r][q * 32 + i * 4 + 2] = __floats2half2_rn(v.z, v.w);
        }
    }
    __syncthreads();

    const int w = tid >> 6, lane = tid & 63;
    const int l15 = lane & 15, kg = lane >> 4;
    const int arow = min(rowBase + w * 16 + l15, N_NODES - 1);   // clamped A row (f16 path)
    const _Float16* hg = (const _Float16*)hin;

    f32x4 acc[8];
    #pragma unroll
    for (int t = 0; t < 8; t++) acc[t] = (f32x4){0.f, 0.f, 0.f, 0.f};

    #pragma unroll
    for (int kt = 0; kt < 4; kt++) {
        f16x8 a;
        if constexpr (F32IN) a = *(f16x8*)&Hl[w * 16 + l15][kt * 32 + kg * 8];
        else                 a = *(const f16x8*)&hg[(size_t)arow * CH + kt * 32 + kg * 8];
        #pragma unroll
        for (int t = 0; t < 8; t++) {
            f16x8 b = *(f16x8*)&Wl[t * 16 + l15][kt * 32 + kg * 8];
            acc[t] = __builtin_amdgcn_mfma_f32_16x16x32_f16(a, b, acc[t], 0, 0, 0);
        }
    }
    if constexpr (F32IN) __syncthreads();   // waves done reading Hl before C overwrite

    // write scaled C into Hl (fp16), rows are wave-private
    #pragma unroll
    for (int r = 0; r < 4; r++) {
        const int lrow = w * 16 + kg * 4 + r;
        const int n = rowBase + lrow;
        const float s = (n < N_NODES) ? dis[n] : 0.f;
        #pragma unroll
        for (int t = 0; t < 8; t++)
            Hl[lrow][t * 16 + l15] = (_Float16)(acc[t][r] * s);
    }
    __syncthreads();

    // coalesced stream-out
    {
        const int r = tid >> 2, q = tid & 3;
        const int n = rowBase + r;
        if (n < N_NODES) {
            #pragma unroll
            for (int i = 0; i < 4; i++)
                *(f16x8*)&((_Float16*)out)[(size_t)n * CH + q * 32 + i * 8] =
                    *(f16x8*)&Hl[r][q * 32 + i * 8];
        }
    }
}

// ---------------- Aggregate: h[n] = relu(dis[n]*(sum_e hs[src_e] + hs[n]) + b) ----------------
// wave = 1 node; 16 lanes/edge x 16B (dwordx4) = 4 edges/instr; indices preloaded
// one-per-lane and broadcast via shfl; csr padded to mult-of-4 with DUMMY -> zero row.
__global__ __launch_bounds__(256) void agg_k(const __half* __restrict__ hs,
                                             const int* __restrict__ offsets,
                                             const int* __restrict__ ecnt,
                                             const unsigned short* __restrict__ csr16,
                                             const float* __restrict__ dis,
                                             const float* __restrict__ bias,
                                             __half* __restrict__ out) {
    const int wid  = threadIdx.x >> 6;
    const int lane = threadIdx.x & 63;
    const int n = blockIdx.x * 4 + wid;
    if (n >= N_NODES) return;
    const int g   = lane >> 4;            // edge slot 0..3
    const int seg = lane & 15;            // 16B segment of the 256B row
    const char* base = (const char*)hs;

    const int beg = offsets[n];
    const int cnt = ecnt[n];

    int myidx = DUMMY16;
    if (lane < cnt) myidx = (int)csr16[beg + lane];   // coalesced 128B

    float acc[8];
    #pragma unroll
    for (int i = 0; i < 8; i++) acc[i] = 0.f;

    if (g == 0) {  // self-loop term, counted once
        f16x8 v = *(const f16x8*)(base + (size_t)n * 256 + seg * 16);
        #pragma unroll
        for (int i = 0; i < 8; i++) acc[i] += (float)v[i];
    }

    const int pcnt  = (cnt + 3) & ~3;
    const int mainc = min(pcnt, 64);
    for (int e = 0; e < mainc; e += 4) {
        int idx = __shfl(myidx, e + g);
        f16x8 v = *(const f16x8*)(base + (size_t)idx * 256 + seg * 16);
        #pragma unroll
        for (int i = 0; i < 8; i++) acc[i] += (float)v[i];
    }
    // rare tail: degree > 64
    for (int e = 64; e < pcnt; e += 4) {
        int idx = (int)csr16[beg + e + g];
        f16x8 v = *(const f16x8*)(base + (size_t)idx * 256 + seg * 16);
        #pragma unroll
        for (int i = 0; i < 8; i++) acc[i] += (float)v[i];
    }

    // reduce across the 4 edge slots (same channels per seg)
    #pragma unroll
    for (int i = 0; i < 8; i++) {
        acc[i] += __shfl_xor(acc[i], 16);
        acc[i] += __shfl_xor(acc[i], 32);
    }

    if (g == 0) {
        const float dn = dis[n];
        float4 b0 = *(const float4*)&bias[seg * 8];
        float4 b1 = *(const float4*)&bias[seg * 8 + 4];
        f16x8 r;
        r[0] = (_Float16)fmaxf(dn * acc[0] + b0.x, 0.f);
        r[1] = (_Float16)fmaxf(dn * acc[1] + b0.y, 0.f);
        r[2] = (_Float16)fmaxf(dn * acc[2] + b0.z, 0.f);
        r[3] = (_Float16)fmaxf(dn * acc[3] + b0.w, 0.f);
        r[4] = (_Float16)fmaxf(dn * acc[4] + b1.x, 0.f);
        r[5] = (_Float16)fmaxf(dn * acc[5] + b1.y, 0.f);
        r[6] = (_Float16)fmaxf(dn * acc[6] + b1.z, 0.f);
        r[7] = (_Float16)fmaxf(dn * acc[7] + b1.w, 0.f);
        *(f16x8*)&((_Float16*)out)[(size_t)n * CH + seg * 8] = r;
    }
}

// ---------------- Global mean pool over fp16 flat h: grid (8 chunks, 64 graphs) ----------------
__global__ __launch_bounds__(256) void pool_k(const __half* __restrict__ h,
                                              const int* __restrict__ gstart,
                                              float* __restrict__ gsum) {
    const __half2* h2 = (const __half2*)h;
    const int g   = blockIdx.y;
    const int s   = blockIdx.x;        // chunk 0..7
    const int tid = threadIdx.x;
    const int r   = tid >> 5;          // 0..7 row slot
    const int cq  = tid & 31;          // channel quad
    const int start = gstart[g], end = gstart[g + 1];
    const int len   = end - start;
    const int chunk = (len + 7) >> 3;
    const int lo = start + s * chunk;
    const int hi = min(lo + chunk, end);

    float4 acc = make_float4(0.f, 0.f, 0.f, 0.f);
    for (int row = lo + r; row < hi; row += 8) {
        float2 a = __half22float2(h2[(size_t)row * 64 + cq * 2]);
        float2 b = __half22float2(h2[(size_t)row * 64 + cq * 2 + 1]);
        acc.x += a.x; acc.y += a.y; acc.z += b.x; acc.w += b.y;
    }

    __shared__ float4 red[256];
    red[tid] = acc;
    __syncthreads();
    #pragma unroll
    for (int off = 4; off >= 1; off >>= 1) {
        if (r < off) {
            float4 o = red[tid + off * 32];
            red[tid].x += o.x; red[tid].y += o.y;
            red[tid].z += o.z; red[tid].w += o.w;
        }
        __syncthreads();
    }
    if (r == 0) {
        float4 v = red[tid];
        atomicAdd(&gsum[g * CH + cq * 4 + 0], v.x);
        atomicAdd(&gsum[g * CH + cq * 4 + 1], v.y);
        atomicAdd(&gsum[g * CH + cq * 4 + 2], v.z);
        atomicAdd(&gsum[g * CH + cq * 4 + 3], v.w);
    }
}

// ---------------- Head ----------------
__global__ __launch_bounds__(128) void head_k(const float* __restrict__ gsum,
                                              const int* __restrict__ gstart,
                                              const float* __restrict__ Wlin,
                                              const float* __restrict__ blin,
                                              float* __restrict__ out) {
    const int t = threadIdx.x;      // 0..127
    const int g = t >> 1;
    const int o = t & 1;
    float cnt = (float)max(gstart[g + 1] - gstart[g], 1);
    float s = 0.f;
    for (int ci = 0; ci < CH; ci++) s += gsum[g * CH + ci] * Wlin[ci * OUTC + o];
    out[g * OUTC + o] = s / cnt + blin[o];
}

// ---------------- launch ----------------

static inline size_t alignup(size_t x) { return (x + 255) & ~(size_t)255; }

extern "C" void kernel_launch(void* const* d_in, const int* in_sizes, int n_in,
                              void* d_out, int out_size, void* d_ws, size_t ws_size,
                              hipStream_t stream) {
    const float* x     = (const float*)d_in[0];
    const int*   eidx  = (const int*)d_in[1];
    const int*   batch = (const int*)d_in[2];
    const float* W0    = (const float*)d_in[3];
    const float* b0    = (const float*)d_in[4];
    const float* W1    = (const float*)d_in[5];
    const float* b1    = (const float*)d_in[6];
    const float* W2    = (const float*)d_in[7];
    const float* b2    = (const float*)d_in[8];
    const float* Wlin  = (const float*)d_in[9];
    const float* blin  = (const float*)d_in[10];
    float* out = (float*)d_out;

    const int* src = eidx;
    const int* dst = eidx + N_EDGES;

    char* p = (char*)d_ws;
    int*    offsets = (int*)p;     p += alignup(N_NODES * 4);
    int*    ecnt    = (int*)p;     p += alignup(N_NODES * 4);
    float*  dis     = (float*)p;   p += alignup(N_NODES * 4);
    int*    bcur    = (int*)p;     p += alignup(NBUCK * 4);
    int*    gstart  = (int*)p;     p += alignup((NGRAPHS + 1) * 4);
    unsigned short* csr16 = (unsigned short*)p; p += alignup((size_t)NBUCK * PADSLOT * 2);
    __half* Wt0     = (__half*)p;  p += alignup(CH * CH * 2);
    __half* Wt1     = (__half*)p;  p += alignup(CH * CH * 2);
    __half* Wt2     = (__half*)p;  p += alignup(CH * CH * 2);
    __half* bufA    = (__half*)p;  p += alignup((size_t)N_NODES * CH * 2);
    __half* hsbuf   = (__half*)p;  p += alignup((size_t)(N_NODES + 1) * CH * 2);
    int*    stage   = (int*)p;     p += alignup((size_t)NBUCK * PADSLOT * 4);
    float*  gsum    = (float*)p;   p += alignup(NGRAPHS * CH * 4);

    setup_k<<<BNDB + 4, 256, 0, stream>>>(batch, gstart, W0, W1, W2,
                                          Wt0, Wt1, Wt2, bcur, hsbuf, gsum);
    bucket_scatter_k<<<F1BLOCKS, 256, 0, stream>>>(src, dst, bcur, stage);
    bucket_build_k<<<NBUCK, 256, 0, stream>>>(stage, bcur, offsets, ecnt, dis, csr16);

    const int GB = (N_NODES + GR - 1) / GR;   // 782 gemm blocks
    const int AB = (N_NODES + 3) / 4;         // agg blocks

    // layer 0: x (f32) -> hsbuf -> bufA
    gemm_mfma_k<true><<<GB, 256, 0, stream>>>(x, Wt0, dis, hsbuf);
    agg_k<<<AB, 256, 0, stream>>>(hsbuf, offsets, ecnt, csr16, dis, b0, bufA);
    // layer 1
    gemm_mfma_k<false><<<GB, 256, 0, stream>>>(bufA, Wt1, dis, hsbuf);
    agg_k<<<AB, 256, 0, stream>>>(hsbuf, offsets, ecnt, csr16, dis, b1, bufA);
    // layer 2
    gemm_mfma_k<false><<<GB, 256, 0, stream>>>(bufA, Wt2, dis, hsbuf);
    agg_k<<<AB, 256, 0, stream>>>(hsbuf, offsets, ecnt, csr16, dis, b2, bufA);

    pool_k<<<dim3(8, NGRAPHS), 256, 0, stream>>>(bufA, gstart, gsum);
    head_k<<<1, 128, 0, stream>>>(gsum, gstart, Wlin, blin, out);
}

// Round 13
// 271.625 us; speedup vs baseline: 1.6567x; 1.0047x over previous
//
#include <hip/hip_runtime.h>
#include <hip/hip_fp16.h>

#define N_NODES   50000
#define N_EDGES   1600000
#define CH        128
#define OUTC      2
#define NGRAPHS   64

#define NBUCK     391          // ceil(N_NODES / 128)
#define EPB       4096         // edges per block in edge-parallel kernels
#define F1BLOCKS  391          // ceil(N_EDGES / EPB)
#define PADSLOT   8192         // fixed stage/csr slot per bucket (max fill ~4500)
#define DUMMY16   ((unsigned short)50000)

#define GR        64           // gemm rows per block
#define BNDB      ((N_NODES + 255) / 256)   // 196 boundary blocks

using f16x8 = __attribute__((ext_vector_type(8))) _Float16;
using f32x4 = __attribute__((ext_vector_type(4))) float;

// ---------------- fused setup: boundary | W transpose | cursors/dummy/gsum ----------------
__global__ __launch_bounds__(256) void setup_k(const int* __restrict__ batch,
                                               int* __restrict__ gstart,
                                               const float* __restrict__ W0,
                                               const float* __restrict__ W1,
                                               const float* __restrict__ W2,
                                               __half* __restrict__ T0,
                                               __half* __restrict__ T1,
                                               __half* __restrict__ T2,
                                               int* __restrict__ bcur,
                                               __half* __restrict__ hsbuf,
                                               float* __restrict__ gsum) {
    const int b = blockIdx.x;
    const int tid = threadIdx.x;
    if (b < BNDB) {
        int i = b * 256 + tid;
        if (i >= N_NODES) return;
        int bc = batch[i];
        if (i == 0) {
            for (int g = 0; g <= bc; g++) gstart[g] = 0;
        } else {
            int bp = batch[i - 1];
            for (int g = bp + 1; g <= bc; g++) gstart[g] = i;
        }
        if (i == N_NODES - 1) {
            for (int g = bc + 1; g <= NGRAPHS; g++) gstart[g] = N_NODES;
        }
    } else if (b < BNDB + 3) {
        const int wi = b - BNDB;
        const float* W = (wi == 0) ? W0 : (wi == 1) ? W1 : W2;
        __half* Wt     = (wi == 0) ? T0 : (wi == 1) ? T1 : T2;
        for (int i = tid; i < CH * CH; i += 256) {
            int k = i >> 7, c = i & 127;
            Wt[c * CH + k] = __float2half(W[i]);
        }
    } else {
        for (int i = tid; i < NBUCK; i += 256) bcur[i] = i * PADSLOT;
        if (tid < 64) ((__half2*)hsbuf)[(size_t)N_NODES * 64 + tid] = __floats2half2_rn(0.f, 0.f);
        for (int i = tid; i < NGRAPHS * CH; i += 256) gsum[i] = 0.f;
    }
}

// ---------------- scatter: 1 LDS-atomic pass (rank from atomicAdd), reg-cached dst ----------------
__global__ __launch_bounds__(256) void bucket_scatter_k(const int* __restrict__ src,
                                                        const int* __restrict__ dst,
                                                        int* __restrict__ bucketCursor,
                                                        int* __restrict__ stage) {
    __shared__ int hist[NBUCK];
    __shared__ int gbase[NBUCK];
    const int tid = threadIdx.x;
    const int e0  = blockIdx.x * EPB;

    for (int i = tid; i < NBUCK; i += 256) hist[i] = 0;
    __syncthreads();

    int dv[16], rk[16];
    #pragma unroll
    for (int i = 0; i < 16; i++) {
        int e = e0 + tid + i * 256;
        dv[i] = (e < N_EDGES) ? dst[e] : -1;
        rk[i] = (dv[i] >= 0) ? atomicAdd(&hist[dv[i] >> 7], 1) : 0;
    }
    __syncthreads();

    for (int i = tid; i < NBUCK; i += 256) {
        int h = hist[i];
        gbase[i] = h ? atomicAdd(&bucketCursor[i], h) : 0;
    }
    __syncthreads();

    #pragma unroll
    for (int i = 0; i < 16; i++) {
        if (dv[i] >= 0) {
            int e = e0 + tid + i * 256;
            int s = src[e];
            int b = dv[i] >> 7;
            stage[gbase[b] + rk[i]] = s | ((dv[i] & 127) << 16);
        }
    }
}

// ---------------- per-bucket: offsets/ecnt/dis + ordered u16 csr padded to mult-of-4 ----------------
__global__ __launch_bounds__(256) void bucket_build_k(const int* __restrict__ stage,
                                                      const int* __restrict__ bcur,
                                                      int* __restrict__ offsets,
                                                      int* __restrict__ ecnt,
                                                      float* __restrict__ dis,
                                                      unsigned short* __restrict__ csr16) {
    __shared__ int lcnt[128];
    __shared__ int lcur[128];
    __shared__ int wtot[2];
    __shared__ int ptotS;
    __shared__ unsigned short loc[PADSLOT];
    const int tid    = threadIdx.x;
    const int b      = blockIdx.x;
    const int first  = b << 7;
    const int nNodes = min(128, N_NODES - first);
    const int pbase  = b * PADSLOT;
    const int bsize  = bcur[b] - pbase;

    if (tid < 128) lcnt[tid] = 0;
    __syncthreads();
    for (int i = tid; i < bsize; i += 256)
        atomicAdd(&lcnt[((unsigned)stage[pbase + i]) >> 16], 1);
    __syncthreads();

    // inclusive scan over padded counts pc = roundup(c,4), 128 threads (2 waves)
    int iv = 0, c = 0, pc = 0;
    if (tid < 128) {
        c  = lcnt[tid];
        pc = (c + 3) & ~3;
        iv = pc;
        #pragma unroll
        for (int d = 1; d < 64; d <<= 1) {
            int o = __shfl_up(iv, d, 64);
            if ((tid & 63) >= d) iv += o;
        }
        if ((tid & 63) == 63) wtot[tid >> 6] = iv;
    }
    __syncthreads();
    if (tid < 128) {
        int add  = (tid >= 64) ? wtot[0] : 0;
        int excl = add + iv - pc;
        lcur[tid] = excl;
        if (tid < nNodes) {
            offsets[first + tid] = pbase + excl;
            ecnt[first + tid]    = c;
            dis[first + tid]     = rsqrtf((float)(c + 1));
        }
        if (tid == 127) ptotS = wtot[0] + wtot[1];
    }
    __syncthreads();
    const int ptot = min(ptotS, PADSLOT);   // multiple of 4

    // vectorized dummy fill (2 u16 per int)
    {
        int* loc4 = (int*)loc;
        const int fill = ((int)DUMMY16 << 16) | (int)DUMMY16;
        for (int i = tid; i < (ptot >> 1); i += 256) loc4[i] = fill;
    }
    __syncthreads();
    for (int i = tid; i < bsize; i += 256) {
        int sd  = stage[pbase + i];
        int pos = atomicAdd(&lcur[((unsigned)sd) >> 16], 1);
        loc[pos] = (unsigned short)(sd & 0xFFFF);
    }
    __syncthreads();
    {
        const int* loc4 = (const int*)loc;
        int* out4 = (int*)&csr16[pbase];    // pbase even -> 4B aligned
        for (int i = tid; i < (ptot >> 1); i += 256) out4[i] = loc4[i];
    }
}

// ---------------- MFMA GEMM: hs = (h @ W) * dis[row], fp16 flat [N][128] out ----------------
template <bool F32IN>
__global__ __launch_bounds__(256) void gemm_mfma_k(const void* __restrict__ hin,
                                                   const __half* __restrict__ Wt,
                                                   const float* __restrict__ dis,
                                                   __half* __restrict__ out) {
    __shared__ _Float16 Hl[GR][136];    // 17.4 KB (input staging f32 path; C staging both)
    __shared__ _Float16 Wl[CH][136];    // 34.8 KB
    const int tid = threadIdx.x;
    const int rowBase = blockIdx.x * GR;

    {
        const int c = tid >> 1, q = tid & 1;
        #pragma unroll
        for (int i = 0; i < 8; i++)
            *(f16x8*)&Wl[c][q * 64 + i * 8] =
                *(const f16x8*)&Wt[c * CH + q * 64 + i * 8];
    }
    if constexpr (F32IN) {
        const int r = tid >> 2, q = tid & 3;
        const int n = rowBase + r;
        const float* h = (const float*)hin;
        #pragma unroll
        for (int i = 0; i < 8; i++) {
            float4 v = make_float4(0.f, 0.f, 0.f, 0.f);
            if (n < N_NODES) v = *(const float4*)&h[(size_t)n * CH + q * 32 + i * 4];
            *(__half2*)&Hl[r][q * 32 + i * 4]     = __floats2half2_rn(v.x, v.y);
            *(__half2*)&Hl[r][q * 32 + i * 4 + 2] = __floats2half2_rn(v.z, v.w);
        }
    }
    __syncthreads();

    const int w = tid >> 6, lane = tid & 63;
    const int l15 = lane & 15, kg = lane >> 4;
    const int arow = min(rowBase + w * 16 + l15, N_NODES - 1);
    const _Float16* hg = (const _Float16*)hin;

    f32x4 acc[8];
    #pragma unroll
    for (int t = 0; t < 8; t++) acc[t] = (f32x4){0.f, 0.f, 0.f, 0.f};

    #pragma unroll
    for (int kt = 0; kt < 4; kt++) {
        f16x8 a;
        if constexpr (F32IN) a = *(f16x8*)&Hl[w * 16 + l15][kt * 32 + kg * 8];
        else                 a = *(const f16x8*)&hg[(size_t)arow * CH + kt * 32 + kg * 8];
        #pragma unroll
        for (int t = 0; t < 8; t++) {
            f16x8 b = *(f16x8*)&Wl[t * 16 + l15][kt * 32 + kg * 8];
            acc[t] = __builtin_amdgcn_mfma_f32_16x16x32_f16(a, b, acc[t], 0, 0, 0);
        }
    }
    if constexpr (F32IN) __syncthreads();

    #pragma unroll
    for (int r = 0; r < 4; r++) {
        const int lrow = w * 16 + kg * 4 + r;
        const int n = rowBase + lrow;
        const float s = (n < N_NODES) ? dis[n] : 0.f;
        #pragma unroll
        for (int t = 0; t < 8; t++)
            Hl[lrow][t * 16 + l15] = (_Float16)(acc[t][r] * s);
    }
    __syncthreads();

    {
        const int r = tid >> 2, q = tid & 3;
        const int n = rowBase + r;
        if (n < N_NODES) {
            #pragma unroll
            for (int i = 0; i < 4; i++)
                *(f16x8*)&((_Float16*)out)[(size_t)n * CH + q * 32 + i * 8] =
                    *(f16x8*)&Hl[r][q * 32 + i * 8];
        }
    }
}

// ---------------- Aggregate: h[n] = relu(dis[n]*(sum_e hs[src_e] + hs[n]) + b) ----------------
__global__ __launch_bounds__(256) void agg_k(const __half* __restrict__ hs,
                                             const int* __restrict__ offsets,
                                             const int* __restrict__ ecnt,
                                             const unsigned short* __restrict__ csr16,
                                             const float* __restrict__ dis,
                                             const float* __restrict__ bias,
                                             __half* __restrict__ out) {
    const int wid  = threadIdx.x >> 6;
    const int lane = threadIdx.x & 63;
    const int n = blockIdx.x * 4 + wid;
    if (n >= N_NODES) return;
    const int g   = lane >> 4;            // edge slot 0..3
    const int seg = lane & 15;            // 16B segment of the 256B row
    const char* base = (const char*)hs;

    const int beg = offsets[n];
    const int cnt = ecnt[n];

    int myidx = DUMMY16;
    if (lane < cnt) myidx = (int)csr16[beg + lane];   // coalesced 128B

    float acc[8];
    #pragma unroll
    for (int i = 0; i < 8; i++) acc[i] = 0.f;

    if (g == 0) {  // self-loop term, counted once
        f16x8 v = *(const f16x8*)(base + (size_t)n * 256 + seg * 16);
        #pragma unroll
        for (int i = 0; i < 8; i++) acc[i] += (float)v[i];
    }

    const int pcnt  = (cnt + 3) & ~3;
    const int mainc = min(pcnt, 64);
    for (int e = 0; e < mainc; e += 4) {
        int idx = __shfl(myidx, e + g);
        f16x8 v = *(const f16x8*)(base + (size_t)idx * 256 + seg * 16);
        #pragma unroll
        for (int i = 0; i < 8; i++) acc[i] += (float)v[i];
    }
    for (int e = 64; e < pcnt; e += 4) {   // rare tail: degree > 64
        int idx = (int)csr16[beg + e + g];
        f16x8 v = *(const f16x8*)(base + (size_t)idx * 256 + seg * 16);
        #pragma unroll
        for (int i = 0; i < 8; i++) acc[i] += (float)v[i];
    }

    #pragma unroll
    for (int i = 0; i < 8; i++) {
        acc[i] += __shfl_xor(acc[i], 16);
        acc[i] += __shfl_xor(acc[i], 32);
    }

    if (g == 0) {
        const float dn = dis[n];
        float4 b0 = *(const float4*)&bias[seg * 8];
        float4 b1 = *(const float4*)&bias[seg * 8 + 4];
        f16x8 r;
        r[0] = (_Float16)fmaxf(dn * acc[0] + b0.x, 0.f);
        r[1] = (_Float16)fmaxf(dn * acc[1] + b0.y, 0.f);
        r[2] = (_Float16)fmaxf(dn * acc[2] + b0.z, 0.f);
        r[3] = (_Float16)fmaxf(dn * acc[3] + b0.w, 0.f);
        r[4] = (_Float16)fmaxf(dn * acc[4] + b1.x, 0.f);
        r[5] = (_Float16)fmaxf(dn * acc[5] + b1.y, 0.f);
        r[6] = (_Float16)fmaxf(dn * acc[6] + b1.z, 0.f);
        r[7] = (_Float16)fmaxf(dn * acc[7] + b1.w, 0.f);
        *(f16x8*)&((_Float16*)out)[(size_t)n * CH + seg * 8] = r;
    }
}

// ---------------- Global mean pool over fp16 flat h: grid (8 chunks, 64 graphs) ----------------
__global__ __launch_bounds__(256) void pool_k(const __half* __restrict__ h,
                                              const int* __restrict__ gstart,
                                              float* __restrict__ gsum) {
    const __half2* h2 = (const __half2*)h;
    const int g   = blockIdx.y;
    const int s   = blockIdx.x;        // chunk 0..7
    const int tid = threadIdx.x;
    const int r   = tid >> 5;          // 0..7 row slot
    const int cq  = tid & 31;          // channel quad
    const int start = gstart[g], end = gstart[g + 1];
    const int len   = end - start;
    const int chunk = (len + 7) >> 3;
    const int lo = start + s * chunk;
    const int hi = min(lo + chunk, end);

    float4 acc = make_float4(0.f, 0.f, 0.f, 0.f);
    for (int row = lo + r; row < hi; row += 8) {
        float2 a = __half22float2(h2[(size_t)row * 64 + cq * 2]);
        float2 b = __half22float2(h2[(size_t)row * 64 + cq * 2 + 1]);
        acc.x += a.x; acc.y += a.y; acc.z += b.x; acc.w += b.y;
    }

    __shared__ float4 red[256];
    red[tid] = acc;
    __syncthreads();
    #pragma unroll
    for (int off = 4; off >= 1; off >>= 1) {
        if (r < off) {
            float4 o = red[tid + off * 32];
            red[tid].x += o.x; red[tid].y += o.y;
            red[tid].z += o.z; red[tid].w += o.w;
        }
        __syncthreads();
    }
    if (r == 0) {
        float4 v = red[tid];
        atomicAdd(&gsum[g * CH + cq * 4 + 0], v.x);
        atomicAdd(&gsum[g * CH + cq * 4 + 1], v.y);
        atomicAdd(&gsum[g * CH + cq * 4 + 2], v.z);
        atomicAdd(&gsum[g * CH + cq * 4 + 3], v.w);
    }
}

// ---------------- Head ----------------
__global__ __launch_bounds__(128) void head_k(const float* __restrict__ gsum,
                                              const int* __restrict__ gstart,
                                              const float* __restrict__ Wlin,
                                              const float* __restrict__ blin,
                                              float* __restrict__ out) {
    const int t = threadIdx.x;      // 0..127
    const int g = t >> 1;
    const int o = t & 1;
    float cnt = (float)max(gstart[g + 1] - gstart[g], 1);
    float s = 0.f;
    for (int ci = 0; ci < CH; ci++) s += gsum[g * CH + ci] * Wlin[ci * OUTC + o];
    out[g * OUTC + o] = s / cnt + blin[o];
}

// ---------------- launch ----------------

static inline size_t alignup(size_t x) { return (x + 255) & ~(size_t)255; }

extern "C" void kernel_launch(void* const* d_in, const int* in_sizes, int n_in,
                              void* d_out, int out_size, void* d_ws, size_t ws_size,
                              hipStream_t stream) {
    const float* x     = (const float*)d_in[0];
    const int*   eidx  = (const int*)d_in[1];
    const int*   batch = (const int*)d_in[2];
    const float* W0    = (const float*)d_in[3];
    const float* b0    = (const float*)d_in[4];
    const float* W1    = (const float*)d_in[5];
    const float* b1    = (const float*)d_in[6];
    const float* W2    = (const float*)d_in[7];
    const float* b2    = (const float*)d_in[8];
    const float* Wlin  = (const float*)d_in[9];
    const float* blin  = (const float*)d_in[10];
    float* out = (float*)d_out;

    const int* src = eidx;
    const int* dst = eidx + N_EDGES;

    char* p = (char*)d_ws;
    int*    offsets = (int*)p;     p += alignup(N_NODES * 4);
    int*    ecnt    = (int*)p;     p += alignup(N_NODES * 4);
    float*  dis     = (float*)p;   p += alignup(N_NODES * 4);
    int*    bcur    = (int*)p;     p += alignup(NBUCK * 4);
    int*    gstart  = (int*)p;     p += alignup((NGRAPHS + 1) * 4);
    unsigned short* csr16 = (unsigned short*)p; p += alignup((size_t)NBUCK * PADSLOT * 2);
    __half* Wt0     = (__half*)p;  p += alignup(CH * CH * 2);
    __half* Wt1     = (__half*)p;  p += alignup(CH * CH * 2);
    __half* Wt2     = (__half*)p;  p += alignup(CH * CH * 2);
    __half* bufA    = (__half*)p;  p += alignup((size_t)N_NODES * CH * 2);
    __half* hsbuf   = (__half*)p;  p += alignup((size_t)(N_NODES + 1) * CH * 2);
    int*    stage   = (int*)p;     p += alignup((size_t)NBUCK * PADSLOT * 4);
    float*  gsum    = (float*)p;   p += alignup(NGRAPHS * CH * 4);

    setup_k<<<BNDB + 4, 256, 0, stream>>>(batch, gstart, W0, W1, W2,
                                          Wt0, Wt1, Wt2, bcur, hsbuf, gsum);
    bucket_scatter_k<<<F1BLOCKS, 256, 0, stream>>>(src, dst, bcur, stage);
    bucket_build_k<<<NBUCK, 256, 0, stream>>>(stage, bcur, offsets, ecnt, dis, csr16);

    const int GB = (N_NODES + GR - 1) / GR;   // 782 gemm blocks
    const int AB = (N_NODES + 3) / 4;         // agg blocks

    // layer 0: x (f32) -> hsbuf -> bufA
    gemm_mfma_k<true><<<GB, 256, 0, stream>>>(x, Wt0, dis, hsbuf);
    agg_k<<<AB, 256, 0, stream>>>(hsbuf, offsets, ecnt, csr16, dis, b0, bufA);
    // layer 1
    gemm_mfma_k<false><<<GB, 256, 0, stream>>>(bufA, Wt1, dis, hsbuf);
    agg_k<<<AB, 256, 0, stream>>>(hsbuf, offsets, ecnt, csr16, dis, b1, bufA);
    // layer 2
    gemm_mfma_k<false><<<GB, 256, 0, stream>>>(bufA, Wt2, dis, hsbuf);
    agg_k<<<AB, 256, 0, stream>>>(hsbuf, offsets, ecnt, csr16, dis, b2, bufA);

    pool_k<<<dim3(8, NGRAPHS), 256, 0, stream>>>(bufA, gstart, gsum);
    head_k<<<1, 128, 0, stream>>>(gsum, gstart, Wlin, blin, out);
}